// Round 1
// baseline (685.189 us; speedup 1.0000x reference)
//
#include <hip/hip_runtime.h>
#include <hip/hip_bf16.h>
#include <math.h>
#include <stdint.h>

typedef __bf16 bf16;
typedef __attribute__((ext_vector_type(8))) __bf16 bf16x8;
typedef __attribute__((ext_vector_type(4))) float f32x4;

typedef __attribute__((address_space(1))) void gas_void;
typedef __attribute__((address_space(3))) void las_void;

#define DEV __device__ __forceinline__

static constexpr int B_ = 8, N_ = 577, D_ = 768, H_ = 12;
static constexpr int M_ = B_ * N_;   // 4616 rows
static constexpr int MP_ = 4736;     // padded to 37*128 for GEMM tiles
static constexpr int NP_ = 640;      // padded N for attention tiles
static constexpr int BH_ = B_ * H_;  // 96
static constexpr float SCALE_ = 0.125f;  // 64^-0.5

DEV void async_cp16(const void* g, void* l) {
  // global -> LDS direct copy, 16B per lane; lds ptr must be wave-uniform base
  __builtin_amdgcn_global_load_lds((gas_void*)g, (las_void*)l, 16, 0, 0);
}
DEV float fast_rcp(float x) { return __builtin_amdgcn_rcpf(x); }
DEV float elu1(float x) { return x > 0.0f ? x + 1.0f : __expf(x); }

// ---------------- f32 -> bf16 convert ----------------
__global__ __launch_bounds__(256) void cvt_kernel(const float* __restrict__ src,
                                                  bf16* __restrict__ dst, int n) {
  int i = blockIdx.x * 256 + threadIdx.x;
  if (i < n) dst[i] = (bf16)src[i];
}

// ---------------- LayerNorm (row of 768) -> bf16 ----------------
__global__ __launch_bounds__(256) void ln_kernel(const float* __restrict__ x,
                                                 const float* __restrict__ w,
                                                 const float* __restrict__ bp,
                                                 bf16* __restrict__ out) {
  const int row = blockIdx.x;
  const int t = threadIdx.x;
  const float* xr = x + (size_t)row * D_;
  float v0 = xr[t], v1 = xr[t + 256], v2 = xr[t + 512];
  float s = v0 + v1 + v2;
  float ss = v0 * v0 + v1 * v1 + v2 * v2;
#pragma unroll
  for (int m = 32; m >= 1; m >>= 1) {
    s += __shfl_down(s, m);
    ss += __shfl_down(ss, m);
  }
  __shared__ float red[8];
  if ((t & 63) == 0) { red[t >> 6] = s; red[4 + (t >> 6)] = ss; }
  __syncthreads();
  s = red[0] + red[1] + red[2] + red[3];
  ss = red[4] + red[5] + red[6] + red[7];
  const float mu = s * (1.0f / D_);
  float var = ss * (1.0f / D_) - mu * mu;
  var = fmaxf(var, 0.0f);
  const float rs = rsqrtf(var + 1e-5f);
  bf16* orow = out + (size_t)row * D_;
  orow[t]       = (bf16)((v0 - mu) * rs * w[t]       + bp[t]);
  orow[t + 256] = (bf16)((v1 - mu) * rs * w[t + 256] + bp[t + 256]);
  orow[t + 512] = (bf16)((v2 - mu) * rs * w[t + 512] + bp[t + 512]);
}

// ---------------- generic GEMM: C[M,N] = A[M,K](bf16) * W[N,K]^T(bf16) ----------------
// m97 structure: 128x128 tile, BK=32, 4 waves, global_load_lds width 16.
enum { EP_BF16 = 0, EP_PROJ = 1, EP_GELU = 2, EP_FC2 = 3 };

template <int EP>
__global__ __launch_bounds__(256) void gemm_bt(
    const bf16* __restrict__ A, const bf16* __restrict__ W,
    int Mlim, int Nn, int K,
    const float* __restrict__ bias, const float* __restrict__ gamma,
    const float* __restrict__ resid,
    bf16* __restrict__ Cb, float* __restrict__ Cf) {
  __shared__ __align__(16) bf16 As[128 * 32];
  __shared__ __align__(16) bf16 Bs[128 * 32];
  const int t = threadIdx.x;
  const int lane = t & 63, wv = t >> 6;
  const int ln = lane & 15, kg = lane >> 4;
  const int wr = wv >> 1, wc = wv & 1;
  const size_t brow = (size_t)blockIdx.y * 128;
  const size_t bcol = (size_t)blockIdx.x * 128;
  const int r0 = t >> 2, gsl = t & 3;  // idx0 = t ; idx1 = t+256 (same gsl)
  const bf16* A0 = A + (brow + r0) * (size_t)K + gsl * 8;
  const bf16* A1 = A + (brow + r0 + 64) * (size_t)K + gsl * 8;
  const bf16* W0 = W + (bcol + r0) * (size_t)K + gsl * 8;
  const bf16* W1 = W + (bcol + r0 + 64) * (size_t)K + gsl * 8;
  f32x4 acc[4][4] = {};
  for (int kk = 0; kk < K; kk += 32) {
    __syncthreads();
    async_cp16(A0 + kk, &As[(wv * 64) * 8]);
    async_cp16(A1 + kk, &As[(256 + wv * 64) * 8]);
    async_cp16(W0 + kk, &Bs[(wv * 64) * 8]);
    async_cp16(W1 + kk, &Bs[(256 + wv * 64) * 8]);
    __syncthreads();
    bf16x8 af[4], bfr[4];
#pragma unroll
    for (int i = 0; i < 4; i++)
      af[i] = *(const bf16x8*)&As[(wr * 64 + i * 16 + ln) * 32 + kg * 8];
#pragma unroll
    for (int j = 0; j < 4; j++)
      bfr[j] = *(const bf16x8*)&Bs[(wc * 64 + j * 16 + ln) * 32 + kg * 8];
#pragma unroll
    for (int i = 0; i < 4; i++)
#pragma unroll
      for (int j = 0; j < 4; j++)
        acc[i][j] = __builtin_amdgcn_mfma_f32_16x16x32_bf16(af[i], bfr[j], acc[i][j], 0, 0, 0);
  }
  // D layout: row = (lane>>4)*4 + r, col = lane&15   [verified m89/m91]
#pragma unroll
  for (int i = 0; i < 4; i++) {
    const int rb = (int)brow + wr * 64 + i * 16 + kg * 4;
#pragma unroll
    for (int j = 0; j < 4; j++) {
      const int col = (int)bcol + wc * 64 + j * 16 + ln;
#pragma unroll
      for (int r = 0; r < 4; r++) {
        const int row = rb + r;
        if (row >= Mlim) continue;
        float v = acc[i][j][r];
        if (EP == EP_BF16) {
          Cb[(size_t)row * Nn + col] = (bf16)v;
        } else if (EP == EP_GELU) {
          v += bias[col];
          v = 0.5f * v * (1.0f + erff(v * 0.70710678118f));
          Cb[(size_t)row * Nn + col] = (bf16)v;
        } else if (EP == EP_PROJ) {
          v += bias[col];
          Cf[(size_t)row * Nn + col] = resid[(size_t)row * Nn + col] + gamma[col] * v;
        } else {  // EP_FC2: accumulate into existing output
          v += bias[col];
          Cf[(size_t)row * Nn + col] += gamma[col] * v;
        }
      }
    }
  }
}

// ---------------- prep: qkv (raw bf16) -> attention operands ----------------
// Qcat[bh][n][0:64]=q*scale, [64:128]=sqrt(clip(elu(cq)+1)) ; Kcat same for k.
// Vt/CVt: [bh][d=64][n=640] transposed ; rowt/colt: |q|^2+sum(cov_q) etc.
__global__ __launch_bounds__(256) void prep_kernel(
    const bf16* __restrict__ qm, const bf16* __restrict__ qc,
    bf16* __restrict__ Qcat, bf16* __restrict__ Kcat,
    bf16* __restrict__ Vt, bf16* __restrict__ CVt,
    float* __restrict__ rowt, float* __restrict__ colt) {
  const int n0 = blockIdx.x * 64;
  const int h = blockIdx.y, b = blockIdx.z;
  const int bh = b * H_ + h;
  const int t = threadIdx.x;
  const int nl = t >> 2, c = t & 3;
  const int n = n0 + nl;
  const bool valid = n < N_;
  __shared__ bf16 vts[64][72], cvts[64][72];
  float q2 = 0.f, cqs = 0.f, k2 = 0.f, cks = 0.f;
  bf16 qo[16], sqo[16], ko[16], sko[16];
  if (valid) {
    const size_t ro = (size_t)(b * N_ + n) * 2304 + h * 64 + c * 16;
#pragma unroll
    for (int half = 0; half < 2; half++) {
      bf16x8 qv8 = *(const bf16x8*)(qm + ro + half * 8);
      bf16x8 kv8 = *(const bf16x8*)(qm + ro + 768 + half * 8);
      bf16x8 vv8 = *(const bf16x8*)(qm + ro + 1536 + half * 8);
      bf16x8 cq8 = *(const bf16x8*)(qc + ro + half * 8);
      bf16x8 ck8 = *(const bf16x8*)(qc + ro + 768 + half * 8);
      bf16x8 cv8 = *(const bf16x8*)(qc + ro + 1536 + half * 8);
#pragma unroll
      for (int i = 0; i < 8; i++) {
        const int d = half * 8 + i;
        float qv = (float)qv8[i] * SCALE_;
        float kv = (float)kv8[i];
        float cq1 = elu1((float)cq8[i]);
        float ck1 = elu1((float)ck8[i]);
        q2 += qv * qv; cqs += cq1; k2 += kv * kv; cks += ck1;
        qo[d] = (bf16)qv; sqo[d] = (bf16)sqrtf(fmaxf(cq1, 1e-24f));
        ko[d] = (bf16)kv; sko[d] = (bf16)sqrtf(fmaxf(ck1, 1e-24f));
        vts[nl][c * 16 + d] = vv8[i];
        cvts[nl][c * 16 + d] = (bf16)elu1((float)cv8[i]);
      }
    }
  } else {
#pragma unroll
    for (int d = 0; d < 16; d++) {
      qo[d] = (bf16)0.f; sqo[d] = (bf16)0.f; ko[d] = (bf16)0.f; sko[d] = (bf16)0.f;
      vts[nl][c * 16 + d] = (bf16)0.f; cvts[nl][c * 16 + d] = (bf16)0.f;
    }
  }
  {
    bf16* qrow = Qcat + ((size_t)bh * NP_ + n) * 128;
    bf16* krow = Kcat + ((size_t)bh * NP_ + n) * 128;
#pragma unroll
    for (int d = 0; d < 16; d++) {
      qrow[c * 16 + d] = qo[d];
      qrow[64 + c * 16 + d] = sqo[d];
      krow[c * 16 + d] = ko[d];
      krow[64 + c * 16 + d] = sko[d];
    }
  }
  float rt = q2 + cqs, ct = k2 + cks;
  rt += __shfl_xor(rt, 1); rt += __shfl_xor(rt, 2);
  ct += __shfl_xor(ct, 1); ct += __shfl_xor(ct, 2);
  if (c == 0) { rowt[(size_t)bh * NP_ + n] = rt; colt[(size_t)bh * NP_ + n] = ct; }
  __syncthreads();
  const int drow = t >> 2;
  const size_t vb = ((size_t)bh * 64 + drow) * NP_ + n0 + c * 16;
#pragma unroll
  for (int i = 0; i < 16; i++) {
    Vt[vb + i] = vts[c * 16 + i][drow];
    CVt[vb + i] = cvts[c * 16 + i][drow];
  }
}

// ---------------- fused attention ----------------
// per block: 64 q-rows of one (b,h); loop 10 j-tiles of 64.
// S = 2*Qcat.Kcat^T - rowt - colt ; e = exp(sigmoid(S)+bias) (no max needed:
// logits bounded); accumulate num_m=Σe·V, num_c=Σe²·CV, den=Σe.
__global__ __launch_bounds__(256) void attn_kernel(
    const bf16* __restrict__ Qcat, const bf16* __restrict__ Kcat,
    const bf16* __restrict__ Vt, const bf16* __restrict__ CVt,
    const float* __restrict__ rowt, const float* __restrict__ colt,
    const float* __restrict__ bias,
    bf16* __restrict__ ctxm, bf16* __restrict__ ctxc) {
  const int i0 = blockIdx.x * 64;
  const int h = blockIdx.y, b = blockIdx.z;
  const int bh = b * H_ + h;
  const int t = threadIdx.x;
  const int lane = t & 63, w = t >> 6;
  const int ln = lane & 15, kg = lane >> 4;
  __shared__ __align__(16) bf16 Ks[64 * 128];   // also used for Q staging
  __shared__ __align__(16) bf16 Vs[64 * 64];
  __shared__ __align__(16) bf16 CVs[64 * 64];
  __shared__ __align__(16) bf16 Ps[64 * 72];
  __shared__ __align__(16) bf16 P2s[64 * 72];

  const bf16* Qg = Qcat + (size_t)bh * NP_ * 128;
  const bf16* Kg = Kcat + (size_t)bh * NP_ * 128;
  const bf16* Vg = Vt + (size_t)bh * 64 * NP_;
  const bf16* CVg = CVt + (size_t)bh * 64 * NP_;

  // stage Q tile (XOR-swizzled source -> linear LDS; read applies same XOR)
#pragma unroll
  for (int q = 0; q < 4; q++) {
    const int idx = q * 256 + t;
    const int row = idx >> 4, sl = idx & 15;
    async_cp16(Qg + (size_t)(i0 + row) * 128 + ((sl ^ (row & 7)) * 8),
               &Ks[(q * 256 + w * 64) * 8]);
  }
  __syncthreads();
  bf16x8 aq[4];
  {
    const int row = w * 16 + ln;
#pragma unroll
    for (int kc = 0; kc < 4; kc++) {
      const int slot = kc * 4 + kg;
      aq[kc] = *(const bf16x8*)&Ks[row * 128 + ((slot ^ (row & 7)) * 8)];
    }
  }
  float rt[4];
#pragma unroll
  for (int r = 0; r < 4; r++) rt[r] = rowt[(size_t)bh * NP_ + i0 + w * 16 + kg * 4 + r];

  f32x4 accm[4] = {}, accc[4] = {};
  float den[4] = {0.f, 0.f, 0.f, 0.f};

  for (int jt = 0; jt < 10; jt++) {
    const int j0 = jt * 64;
    __syncthreads();  // previous tile reads done before overwrite
#pragma unroll
    for (int q = 0; q < 4; q++) {
      const int idx = q * 256 + t;
      const int row = idx >> 4, sl = idx & 15;
      async_cp16(Kg + (size_t)(j0 + row) * 128 + ((sl ^ (row & 7)) * 8),
                 &Ks[(q * 256 + w * 64) * 8]);
    }
#pragma unroll
    for (int q = 0; q < 2; q++) {
      const int idx = q * 256 + t;
      const int row = idx >> 3, sl = idx & 7;
      async_cp16(Vg + (size_t)row * NP_ + j0 + ((sl ^ (row & 7)) * 8),
                 &Vs[(q * 256 + w * 64) * 8]);
      async_cp16(CVg + (size_t)row * NP_ + j0 + ((sl ^ (row & 7)) * 8),
                 &CVs[(q * 256 + w * 64) * 8]);
    }
    __syncthreads();
    // QK^T (K=128) + epilogue
#pragma unroll
    for (int js = 0; js < 4; js++) {
      f32x4 s = {};
#pragma unroll
      for (int kc = 0; kc < 4; kc++) {
        const int row = js * 16 + ln;
        const int slot = kc * 4 + kg;
        bf16x8 bk = *(const bf16x8*)&Ks[row * 128 + ((slot ^ (row & 7)) * 8)];
        s = __builtin_amdgcn_mfma_f32_16x16x32_bf16(aq[kc], bk, s, 0, 0, 0);
      }
      const int jg = j0 + js * 16 + ln;
      const float ct = colt[(size_t)bh * NP_ + jg];
#pragma unroll
      for (int r = 0; r < 4; r++) {
        const int ig = i0 + w * 16 + kg * 4 + r;
        const float S = 2.0f * s[r] - rt[r] - ct;
        const float sig = fast_rcp(1.0f + __expf(-S));
        const float bia = (ig < N_ && jg < N_)
                              ? bias[((size_t)h * N_ + ig) * N_ + jg] : 0.0f;
        float e = __expf(sig + bia);
        if (jg >= N_) e = 0.0f;
        const bf16 eb = (bf16)e;
        const float ef = (float)eb;
        den[r] += ef;
        Ps[(w * 16 + kg * 4 + r) * 72 + js * 16 + ln] = eb;
        P2s[(w * 16 + kg * 4 + r) * 72 + js * 16 + ln] = (bf16)(ef * ef);
      }
    }
    // PV: own wave's P rows only (no cross-wave dependency)
#pragma unroll
    for (int ks = 0; ks < 2; ks++) {
      const int prow = w * 16 + ln;
      bf16x8 pa = *(const bf16x8*)&Ps[prow * 72 + ks * 32 + kg * 8];
      bf16x8 p2a = *(const bf16x8*)&P2s[prow * 72 + ks * 32 + kg * 8];
#pragma unroll
      for (int nt = 0; nt < 4; nt++) {
        const int vrow = nt * 16 + ln;
        const int slot = ks * 4 + kg;
        bf16x8 vb = *(const bf16x8*)&Vs[vrow * 64 + ((slot ^ (vrow & 7)) * 8)];
        bf16x8 cvb = *(const bf16x8*)&CVs[vrow * 64 + ((slot ^ (vrow & 7)) * 8)];
        accm[nt] = __builtin_amdgcn_mfma_f32_16x16x32_bf16(pa, vb, accm[nt], 0, 0, 0);
        accc[nt] = __builtin_amdgcn_mfma_f32_16x16x32_bf16(p2a, cvb, accc[nt], 0, 0, 0);
      }
    }
  }
  // den: sum across the 16 column-lanes of each group
#pragma unroll
  for (int r = 0; r < 4; r++) {
    float d = den[r];
    d += __shfl_xor(d, 1); d += __shfl_xor(d, 2);
    d += __shfl_xor(d, 4); d += __shfl_xor(d, 8);
    den[r] = d;
  }
#pragma unroll
  for (int r = 0; r < 4; r++) {
    const int ig = i0 + w * 16 + kg * 4 + r;
    if (ig < N_) {
      const float inv = fast_rcp(den[r]);
      const float inv2 = inv * inv;
      const size_t base = (size_t)(b * N_ + ig) * D_ + h * 64;
#pragma unroll
      for (int nt = 0; nt < 4; nt++) {
        ctxm[base + nt * 16 + ln] = (bf16)(accm[nt][r] * inv);
        ctxc[base + nt * 16 + ln] = (bf16)(accc[nt][r] * inv2);
      }
    }
  }
}

// ---------------- host launch ----------------
extern "C" void kernel_launch(void* const* d_in, const int* in_sizes, int n_in,
                              void* d_out, int out_size, void* d_ws, size_t ws_size,
                              hipStream_t stream) {
  const float* x_mean = (const float*)d_in[0];
  const float* x_cov  = (const float*)d_in[1];
  const float* rpb    = (const float*)d_in[2];
  const float* n1w    = (const float*)d_in[3];
  const float* n1b    = (const float*)d_in[4];
  const float* qkvw   = (const float*)d_in[5];
  const float* projw  = (const float*)d_in[6];
  const float* projb  = (const float*)d_in[7];
  const float* cprojw = (const float*)d_in[8];
  const float* cprojb = (const float*)d_in[9];
  const float* n2w    = (const float*)d_in[10];
  const float* n2b    = (const float*)d_in[11];
  const float* fc1w   = (const float*)d_in[12];
  const float* fc1b   = (const float*)d_in[13];
  const float* fc2w   = (const float*)d_in[14];
  const float* fc2b   = (const float*)d_in[15];
  const float* g1     = (const float*)d_in[16];
  const float* g2     = (const float*)d_in[17];
  (void)in_sizes; (void)n_in; (void)out_size; (void)ws_size;

  char* ws = (char*)d_ws;
  size_t off = 0;
  auto take = [&](size_t bytes) {
    char* p = ws + off;
    off += (bytes + 255) & ~(size_t)255;
    return p;
  };
  bf16* wq   = (bf16*)take((size_t)2304 * 768 * 2);
  bf16* wp   = (bf16*)take((size_t)768 * 768 * 2);
  bf16* wcp  = (bf16*)take((size_t)768 * 768 * 2);
  bf16* wf1  = (bf16*)take((size_t)3072 * 768 * 2);
  bf16* wf2  = (bf16*)take((size_t)768 * 3072 * 2);
  bf16* xmn  = (bf16*)take((size_t)MP_ * 768 * 2);
  bf16* xcn  = (bf16*)take((size_t)MP_ * 768 * 2);
  char* R    = take((size_t)2 * MP_ * 3072 * 2);  // qkv (phase 1) / mlp-hidden (phase 2)
  bf16* qkvm = (bf16*)R;
  bf16* qkvc = (bf16*)(R + (size_t)M_ * 2304 * 2);
  bf16* hm   = (bf16*)R;
  bf16* hc   = (bf16*)(R + (size_t)MP_ * 3072 * 2);
  bf16* Qcat = (bf16*)take((size_t)BH_ * NP_ * 128 * 2);
  bf16* Kcat = (bf16*)take((size_t)BH_ * NP_ * 128 * 2);
  bf16* Vt   = (bf16*)take((size_t)BH_ * 64 * NP_ * 2);
  bf16* CVt  = (bf16*)take((size_t)BH_ * 64 * NP_ * 2);
  float* rowt = (float*)take((size_t)BH_ * NP_ * 4);
  float* colt = (float*)take((size_t)BH_ * NP_ * 4);
  bf16* ctxm = (bf16*)take((size_t)MP_ * 768 * 2);
  bf16* ctxc = (bf16*)take((size_t)MP_ * 768 * 2);

  float* outm = (float*)d_out;
  float* outc = outm + (size_t)M_ * D_;

  // weights -> bf16
  cvt_kernel<<<(2304 * 768 + 255) / 256, 256, 0, stream>>>(qkvw, wq, 2304 * 768);
  cvt_kernel<<<(768 * 768 + 255) / 256, 256, 0, stream>>>(projw, wp, 768 * 768);
  cvt_kernel<<<(768 * 768 + 255) / 256, 256, 0, stream>>>(cprojw, wcp, 768 * 768);
  cvt_kernel<<<(3072 * 768 + 255) / 256, 256, 0, stream>>>(fc1w, wf1, 3072 * 768);
  cvt_kernel<<<(768 * 3072 + 255) / 256, 256, 0, stream>>>(fc2w, wf2, 768 * 3072);
  // LN1
  ln_kernel<<<M_, 256, 0, stream>>>(x_mean, n1w, n1b, xmn);
  ln_kernel<<<M_, 256, 0, stream>>>(x_cov, n1w, n1b, xcn);
  // qkv GEMMs (raw bf16 out)
  gemm_bt<EP_BF16><<<dim3(18, 37), 256, 0, stream>>>(xmn, wq, M_, 2304, 768,
      nullptr, nullptr, nullptr, qkvm, nullptr);
  gemm_bt<EP_BF16><<<dim3(18, 37), 256, 0, stream>>>(xcn, wq, M_, 2304, 768,
      nullptr, nullptr, nullptr, qkvc, nullptr);
  // attention operand prep
  prep_kernel<<<dim3(10, 12, 8), 256, 0, stream>>>(qkvm, qkvc, Qcat, Kcat, Vt, CVt,
                                                   rowt, colt);
  // fused attention
  attn_kernel<<<dim3(10, 12, 8), 256, 0, stream>>>(Qcat, Kcat, Vt, CVt, rowt, colt,
                                                   rpb, ctxm, ctxc);
  // proj + residual (writes d_out)
  gemm_bt<EP_PROJ><<<dim3(6, 37), 256, 0, stream>>>(ctxm, wp, M_, 768, 768,
      projb, g1, x_mean, nullptr, outm);
  gemm_bt<EP_PROJ><<<dim3(6, 37), 256, 0, stream>>>(ctxc, wcp, M_, 768, 768,
      cprojb, g1, x_cov, nullptr, outc);
  // LN2 (reads d_out)
  ln_kernel<<<M_, 256, 0, stream>>>(outm, n2w, n2b, xmn);
  ln_kernel<<<M_, 256, 0, stream>>>(outc, n2w, n2b, xcn);
  // fc1 + exact gelu
  gemm_bt<EP_GELU><<<dim3(24, 37), 256, 0, stream>>>(xmn, wf1, M_, 3072, 768,
      fc1b, nullptr, nullptr, hm, nullptr);
  gemm_bt<EP_GELU><<<dim3(24, 37), 256, 0, stream>>>(xcn, wf1, M_, 3072, 768,
      fc1b, nullptr, nullptr, hc, nullptr);
  // fc2, accumulate into d_out
  gemm_bt<EP_FC2><<<dim3(6, 37), 256, 0, stream>>>(hm, wf2, M_, 768, 3072,
      fc2b, g2, nullptr, nullptr, outm);
  gemm_bt<EP_FC2><<<dim3(6, 37), 256, 0, stream>>>(hc, wf2, M_, 768, 3072,
      fc2b, g2, nullptr, nullptr, outc);
}

// Round 2
// 437.779 us; speedup vs baseline: 1.5651x; 1.5651x over previous
//
#include <hip/hip_runtime.h>
#include <hip/hip_bf16.h>
#include <math.h>
#include <stdint.h>

typedef __bf16 bf16;
typedef __attribute__((ext_vector_type(8))) __bf16 bf16x8;
typedef __attribute__((ext_vector_type(4))) float f32x4;

typedef __attribute__((address_space(1))) void gas_void;
typedef __attribute__((address_space(3))) void las_void;

#define DEV __device__ __forceinline__

static constexpr int B_ = 8, N_ = 577, D_ = 768, H_ = 12;
static constexpr int M_ = B_ * N_;   // 4616 rows
static constexpr int MP_ = 4736;     // padded to 37*128 for GEMM tiles
static constexpr int NP_ = 640;      // padded N for attention tiles
static constexpr int BH_ = B_ * H_;  // 96
static constexpr float SCALE_ = 0.125f;  // 64^-0.5

DEV void async_cp16(const void* g, void* l) {
  __builtin_amdgcn_global_load_lds((gas_void*)g, (las_void*)l, 16, 0, 0);
}
DEV float fast_rcp(float x) { return __builtin_amdgcn_rcpf(x); }
DEV float elu1(float x) { return x > 0.0f ? x + 1.0f : __expf(x); }

// ---------------- f32 -> bf16 convert ----------------
__global__ __launch_bounds__(256) void cvt_kernel(const float* __restrict__ src,
                                                  bf16* __restrict__ dst, int n) {
  int i = blockIdx.x * 256 + threadIdx.x;
  if (i < n) dst[i] = (bf16)src[i];
}

// ---------------- LayerNorm (row of 768) -> bf16 ----------------
__global__ __launch_bounds__(256) void ln_kernel(const float* __restrict__ x,
                                                 const float* __restrict__ w,
                                                 const float* __restrict__ bp,
                                                 bf16* __restrict__ out) {
  const int row = blockIdx.x;
  const int t = threadIdx.x;
  const float* xr = x + (size_t)row * D_;
  float v0 = xr[t], v1 = xr[t + 256], v2 = xr[t + 512];
  float s = v0 + v1 + v2;
  float ss = v0 * v0 + v1 * v1 + v2 * v2;
#pragma unroll
  for (int m = 32; m >= 1; m >>= 1) {
    s += __shfl_down(s, m);
    ss += __shfl_down(ss, m);
  }
  __shared__ float red[8];
  if ((t & 63) == 0) { red[t >> 6] = s; red[4 + (t >> 6)] = ss; }
  __syncthreads();
  s = red[0] + red[1] + red[2] + red[3];
  ss = red[4] + red[5] + red[6] + red[7];
  const float mu = s * (1.0f / D_);
  float var = ss * (1.0f / D_) - mu * mu;
  var = fmaxf(var, 0.0f);
  const float rs = rsqrtf(var + 1e-5f);
  bf16* orow = out + (size_t)row * D_;
  orow[t]       = (bf16)((v0 - mu) * rs * w[t]       + bp[t]);
  orow[t + 256] = (bf16)((v1 - mu) * rs * w[t + 256] + bp[t + 256]);
  orow[t + 512] = (bf16)((v2 - mu) * rs * w[t + 512] + bp[t + 512]);
}

// ---------------- dual-stream GEMM: C[2MP,N] = A[2MP,K](bf16) * Ws[N,K]^T ----------------
// Streams stacked on M: rows [0,MP) = mean stream, [MP,2MP) = cov stream.
// Per-block stream select (weights/bias/resid/out) by blockIdx.y.
enum { EP_BF16 = 0, EP_PROJ = 1, EP_GELU = 2, EP_FC2 = 3 };

template <int EP>
__global__ __launch_bounds__(256) void gemm_bt(
    const bf16* __restrict__ A, const bf16* __restrict__ W0,
    const bf16* __restrict__ W1, int Nn, int K,
    const float* __restrict__ bias0, const float* __restrict__ bias1,
    const float* __restrict__ gamma,
    const float* __restrict__ resid0, const float* __restrict__ resid1,
    bf16* __restrict__ Cb, float* __restrict__ Cf0, float* __restrict__ Cf1) {
  __shared__ __align__(16) bf16 As[128 * 32];
  __shared__ __align__(16) bf16 Bs[128 * 32];
  const int t = threadIdx.x;
  const int lane = t & 63, wv = t >> 6;
  const int ln = lane & 15, kg = lane >> 4;
  const int wr = wv >> 1, wc = wv & 1;
  const int s = (int)(blockIdx.y >= (MP_ / 128));
  const bf16* W = s ? W1 : W0;
  const size_t brow = (size_t)blockIdx.y * 128;
  const size_t bcol = (size_t)blockIdx.x * 128;
  const int r0 = t >> 2, gsl = t & 3;
  const bf16* A0 = A + (brow + r0) * (size_t)K + gsl * 8;
  const bf16* A1 = A + (brow + r0 + 64) * (size_t)K + gsl * 8;
  const bf16* W0p = W + (bcol + r0) * (size_t)K + gsl * 8;
  const bf16* W1p = W + (bcol + r0 + 64) * (size_t)K + gsl * 8;
  f32x4 acc[4][4] = {};
  for (int kk = 0; kk < K; kk += 32) {
    __syncthreads();
    async_cp16(A0 + kk, &As[(wv * 64) * 8]);
    async_cp16(A1 + kk, &As[(256 + wv * 64) * 8]);
    async_cp16(W0p + kk, &Bs[(wv * 64) * 8]);
    async_cp16(W1p + kk, &Bs[(256 + wv * 64) * 8]);
    __syncthreads();
    bf16x8 af[4], bfr[4];
#pragma unroll
    for (int i = 0; i < 4; i++)
      af[i] = *(const bf16x8*)&As[(wr * 64 + i * 16 + ln) * 32 + kg * 8];
#pragma unroll
    for (int j = 0; j < 4; j++)
      bfr[j] = *(const bf16x8*)&Bs[(wc * 64 + j * 16 + ln) * 32 + kg * 8];
#pragma unroll
    for (int i = 0; i < 4; i++)
#pragma unroll
      for (int j = 0; j < 4; j++)
        acc[i][j] = __builtin_amdgcn_mfma_f32_16x16x32_bf16(af[i], bfr[j], acc[i][j], 0, 0, 0);
  }
  const float* biasS = s ? bias1 : bias0;
  const float* residS = s ? resid1 : resid0;
  float* CfS = s ? Cf1 : Cf0;
  // D layout: row = (lane>>4)*4 + r, col = lane&15
#pragma unroll
  for (int i = 0; i < 4; i++) {
    const int rb = (int)brow + wr * 64 + i * 16 + kg * 4;
#pragma unroll
    for (int j = 0; j < 4; j++) {
      const int col = (int)bcol + wc * 64 + j * 16 + ln;
#pragma unroll
      for (int r = 0; r < 4; r++) {
        const int row = rb + r;  // combined-row index
        float v = acc[i][j][r];
        if (EP == EP_BF16) {
          Cb[(size_t)row * Nn + col] = (bf16)v;
        } else if (EP == EP_GELU) {
          v += biasS[col];
          v = 0.5f * v * (1.0f + erff(v * 0.70710678118f));
          Cb[(size_t)row * Nn + col] = (bf16)v;
        } else {
          const int r2 = row - s * MP_;
          if (r2 < M_) {
            v += biasS[col];
            if (EP == EP_PROJ) {
              CfS[(size_t)r2 * Nn + col] = residS[(size_t)r2 * Nn + col] + gamma[col] * v;
            } else {  // EP_FC2
              CfS[(size_t)r2 * Nn + col] += gamma[col] * v;
            }
          }
        }
      }
    }
  }
}

// ---------------- prep: qkv (raw bf16) -> attention operands ----------------
__global__ __launch_bounds__(256) void prep_kernel(
    const bf16* __restrict__ qm, const bf16* __restrict__ qc,
    bf16* __restrict__ Qcat, bf16* __restrict__ Kcat,
    bf16* __restrict__ Vt, bf16* __restrict__ CVt,
    float* __restrict__ rowt, float* __restrict__ colt) {
  const int n0 = blockIdx.x * 64;
  const int h = blockIdx.y, b = blockIdx.z;
  const int bh = b * H_ + h;
  const int t = threadIdx.x;
  const int nl = t >> 2, c = t & 3;
  const int n = n0 + nl;
  const bool valid = n < N_;
  __shared__ bf16 vts[64][72], cvts[64][72];
  float q2 = 0.f, cqs = 0.f, k2 = 0.f, cks = 0.f;
  bf16 qo[16], sqo[16], ko[16], sko[16];
  if (valid) {
    const size_t ro = (size_t)(b * N_ + n) * 2304 + h * 64 + c * 16;
#pragma unroll
    for (int half = 0; half < 2; half++) {
      bf16x8 qv8 = *(const bf16x8*)(qm + ro + half * 8);
      bf16x8 kv8 = *(const bf16x8*)(qm + ro + 768 + half * 8);
      bf16x8 vv8 = *(const bf16x8*)(qm + ro + 1536 + half * 8);
      bf16x8 cq8 = *(const bf16x8*)(qc + ro + half * 8);
      bf16x8 ck8 = *(const bf16x8*)(qc + ro + 768 + half * 8);
      bf16x8 cv8 = *(const bf16x8*)(qc + ro + 1536 + half * 8);
#pragma unroll
      for (int i = 0; i < 8; i++) {
        const int d = half * 8 + i;
        float qv = (float)qv8[i] * SCALE_;
        float kv = (float)kv8[i];
        float cq1 = elu1((float)cq8[i]);
        float ck1 = elu1((float)ck8[i]);
        q2 += qv * qv; cqs += cq1; k2 += kv * kv; cks += ck1;
        qo[d] = (bf16)qv; sqo[d] = (bf16)sqrtf(fmaxf(cq1, 1e-24f));
        ko[d] = (bf16)kv; sko[d] = (bf16)sqrtf(fmaxf(ck1, 1e-24f));
        vts[nl][c * 16 + d] = vv8[i];
        cvts[nl][c * 16 + d] = (bf16)elu1((float)cv8[i]);
      }
    }
  } else {
#pragma unroll
    for (int d = 0; d < 16; d++) {
      qo[d] = (bf16)0.f; sqo[d] = (bf16)0.f; ko[d] = (bf16)0.f; sko[d] = (bf16)0.f;
      vts[nl][c * 16 + d] = (bf16)0.f; cvts[nl][c * 16 + d] = (bf16)0.f;
    }
  }
  {
    bf16* qrow = Qcat + ((size_t)bh * NP_ + n) * 128;
    bf16* krow = Kcat + ((size_t)bh * NP_ + n) * 128;
#pragma unroll
    for (int d = 0; d < 16; d++) {
      qrow[c * 16 + d] = qo[d];
      qrow[64 + c * 16 + d] = sqo[d];
      krow[c * 16 + d] = ko[d];
      krow[64 + c * 16 + d] = sko[d];
    }
  }
  float rt = q2 + cqs, ct = k2 + cks;
  rt += __shfl_xor(rt, 1); rt += __shfl_xor(rt, 2);
  ct += __shfl_xor(ct, 1); ct += __shfl_xor(ct, 2);
  if (c == 0) { rowt[(size_t)bh * NP_ + n] = rt; colt[(size_t)bh * NP_ + n] = ct; }
  __syncthreads();
  const int drow = t >> 2;
  const size_t vb = ((size_t)bh * 64 + drow) * NP_ + n0 + c * 16;
#pragma unroll
  for (int i = 0; i < 16; i++) {
    Vt[vb + i] = vts[c * 16 + i][drow];
    CVt[vb + i] = cvts[c * 16 + i][drow];
  }
}

// ---------------- fused attention ----------------
// 1-D grid of 960, XCD-grouped: all 10 i-tiles of one (b,h) on the same XCD
// so K/V/CV stay L2-resident. Bias (bf16) prefetched to regs per tile.
__global__ __launch_bounds__(256) void attn_kernel(
    const bf16* __restrict__ Qcat, const bf16* __restrict__ Kcat,
    const bf16* __restrict__ Vt, const bf16* __restrict__ CVt,
    const float* __restrict__ rowt, const float* __restrict__ colt,
    const bf16* __restrict__ bias,
    bf16* __restrict__ ctxm, bf16* __restrict__ ctxc) {
  const int id = blockIdx.x;            // 0..959
  const int xcd = id & 7, slot = id >> 3;
  const int g = xcd + 8 * (slot / 10);  // bh 0..95
  const int it = slot % 10;
  const int b = g / H_, h = g % H_;
  const int bh = g;
  const int i0 = it * 64;
  const int t = threadIdx.x;
  const int lane = t & 63, w = t >> 6;
  const int ln = lane & 15, kg = lane >> 4;
  __shared__ __align__(16) bf16 Ks[64 * 128];   // also used for Q staging
  __shared__ __align__(16) bf16 Vs[64 * 64];
  __shared__ __align__(16) bf16 CVs[64 * 64];
  __shared__ __align__(16) bf16 Ps[64 * 72];

  const bf16* Qg = Qcat + (size_t)bh * NP_ * 128;
  const bf16* Kg = Kcat + (size_t)bh * NP_ * 128;
  const bf16* Vg = Vt + (size_t)bh * 64 * NP_;
  const bf16* CVg = CVt + (size_t)bh * 64 * NP_;

  // stage Q tile (XOR-swizzled source -> linear LDS; read applies same XOR)
#pragma unroll
  for (int q = 0; q < 4; q++) {
    const int idx = q * 256 + t;
    const int row = idx >> 4, sl = idx & 15;
    async_cp16(Qg + (size_t)(i0 + row) * 128 + ((sl ^ (row & 7)) * 8),
               &Ks[(q * 256 + w * 64) * 8]);
  }
  __syncthreads();
  bf16x8 aq[4];
  {
    const int row = w * 16 + ln;
#pragma unroll
    for (int kc = 0; kc < 4; kc++) {
      const int slot2 = kc * 4 + kg;
      aq[kc] = *(const bf16x8*)&Ks[row * 128 + ((slot2 ^ (row & 7)) * 8)];
    }
  }
  float rt[4];
#pragma unroll
  for (int r = 0; r < 4; r++) rt[r] = rowt[(size_t)bh * NP_ + i0 + w * 16 + kg * 4 + r];

  f32x4 accm[4] = {}, accc[4] = {};
  float den[4] = {0.f, 0.f, 0.f, 0.f};
  const int igb = i0 + w * 16 + kg * 4;

  for (int jt = 0; jt < 10; jt++) {
    const int j0 = jt * 64;
    __syncthreads();  // previous tile reads done before overwrite
#pragma unroll
    for (int q = 0; q < 4; q++) {
      const int idx = q * 256 + t;
      const int row = idx >> 4, sl = idx & 15;
      async_cp16(Kg + (size_t)(j0 + row) * 128 + ((sl ^ (row & 7)) * 8),
                 &Ks[(q * 256 + w * 64) * 8]);
    }
#pragma unroll
    for (int q = 0; q < 2; q++) {
      const int idx = q * 256 + t;
      const int row = idx >> 3, sl = idx & 7;
      async_cp16(Vg + (size_t)row * NP_ + j0 + ((sl ^ (row & 7)) * 8),
                 &Vs[(q * 256 + w * 64) * 8]);
      async_cp16(CVg + (size_t)row * NP_ + j0 + ((sl ^ (row & 7)) * 8),
                 &CVs[(q * 256 + w * 64) * 8]);
    }
    // prefetch bias + colt for this tile into regs (overlaps staging drain)
    float bb[4][4], ctb[4];
#pragma unroll
    for (int js = 0; js < 4; js++) {
      const int jg = j0 + js * 16 + ln;
      const int jc = jg < N_ ? jg : N_ - 1;
      ctb[js] = colt[(size_t)bh * NP_ + jg];
#pragma unroll
      for (int r = 0; r < 4; r++) {
        const int ic = (igb + r) < N_ ? (igb + r) : N_ - 1;
        bb[js][r] = (float)bias[((size_t)h * N_ + ic) * N_ + jc];
      }
    }
    __syncthreads();
    // QK^T (K=128) + epilogue
#pragma unroll
    for (int js = 0; js < 4; js++) {
      f32x4 sv = {};
#pragma unroll
      for (int kc = 0; kc < 4; kc++) {
        const int row = js * 16 + ln;
        const int slot2 = kc * 4 + kg;
        bf16x8 bk = *(const bf16x8*)&Ks[row * 128 + ((slot2 ^ (row & 7)) * 8)];
        sv = __builtin_amdgcn_mfma_f32_16x16x32_bf16(aq[kc], bk, sv, 0, 0, 0);
      }
      const int jg = j0 + js * 16 + ln;
#pragma unroll
      for (int r = 0; r < 4; r++) {
        const float S = 2.0f * sv[r] - rt[r] - ctb[js];
        const float sig = fast_rcp(1.0f + __expf(-S));
        float e = __expf(sig + bb[js][r]);
        if (jg >= N_) e = 0.0f;
        const bf16 eb = (bf16)e;
        den[r] += (float)eb;
        Ps[(w * 16 + kg * 4 + r) * 72 + js * 16 + ln] = eb;
      }
    }
    // PV: own wave's P rows only (no cross-wave dependency)
#pragma unroll
    for (int ks = 0; ks < 2; ks++) {
      const int prow = w * 16 + ln;
      bf16x8 pa = *(const bf16x8*)&Ps[prow * 72 + ks * 32 + kg * 8];
      bf16x8 p2a;
#pragma unroll
      for (int i = 0; i < 8; i++) {
        const float pf = (float)pa[i];
        p2a[i] = (bf16)(pf * pf);
      }
#pragma unroll
      for (int nt = 0; nt < 4; nt++) {
        const int vrow = nt * 16 + ln;
        const int slot2 = ks * 4 + kg;
        bf16x8 vb = *(const bf16x8*)&Vs[vrow * 64 + ((slot2 ^ (vrow & 7)) * 8)];
        bf16x8 cvb = *(const bf16x8*)&CVs[vrow * 64 + ((slot2 ^ (vrow & 7)) * 8)];
        accm[nt] = __builtin_amdgcn_mfma_f32_16x16x32_bf16(pa, vb, accm[nt], 0, 0, 0);
        accc[nt] = __builtin_amdgcn_mfma_f32_16x16x32_bf16(p2a, cvb, accc[nt], 0, 0, 0);
      }
    }
  }
#pragma unroll
  for (int r = 0; r < 4; r++) {
    float d = den[r];
    d += __shfl_xor(d, 1); d += __shfl_xor(d, 2);
    d += __shfl_xor(d, 4); d += __shfl_xor(d, 8);
    den[r] = d;
  }
#pragma unroll
  for (int r = 0; r < 4; r++) {
    const int ig = i0 + w * 16 + kg * 4 + r;
    if (ig < N_) {
      const float inv = fast_rcp(den[r]);
      const float inv2 = inv * inv;
      const size_t base = (size_t)(b * N_ + ig) * D_ + h * 64;
#pragma unroll
      for (int nt = 0; nt < 4; nt++) {
        ctxm[base + nt * 16 + ln] = (bf16)(accm[nt][r] * inv);
        ctxc[base + nt * 16 + ln] = (bf16)(accc[nt][r] * inv2);
      }
    }
  }
}

// ---------------- host launch ----------------
extern "C" void kernel_launch(void* const* d_in, const int* in_sizes, int n_in,
                              void* d_out, int out_size, void* d_ws, size_t ws_size,
                              hipStream_t stream) {
  const float* x_mean = (const float*)d_in[0];
  const float* x_cov  = (const float*)d_in[1];
  const float* rpb    = (const float*)d_in[2];
  const float* n1w    = (const float*)d_in[3];
  const float* n1b    = (const float*)d_in[4];
  const float* qkvw   = (const float*)d_in[5];
  const float* projw  = (const float*)d_in[6];
  const float* projb  = (const float*)d_in[7];
  const float* cprojw = (const float*)d_in[8];
  const float* cprojb = (const float*)d_in[9];
  const float* n2w    = (const float*)d_in[10];
  const float* n2b    = (const float*)d_in[11];
  const float* fc1w   = (const float*)d_in[12];
  const float* fc1b   = (const float*)d_in[13];
  const float* fc2w   = (const float*)d_in[14];
  const float* fc2b   = (const float*)d_in[15];
  const float* g1     = (const float*)d_in[16];
  const float* g2     = (const float*)d_in[17];
  (void)in_sizes; (void)n_in; (void)out_size; (void)ws_size;

  char* ws = (char*)d_ws;
  size_t off = 0;
  auto take = [&](size_t bytes) {
    char* p = ws + off;
    off += (bytes + 255) & ~(size_t)255;
    return p;
  };
  bf16* wq   = (bf16*)take((size_t)2304 * 768 * 2);
  bf16* wp   = (bf16*)take((size_t)768 * 768 * 2);
  bf16* wcp  = (bf16*)take((size_t)768 * 768 * 2);
  bf16* wf1  = (bf16*)take((size_t)3072 * 768 * 2);
  bf16* wf2  = (bf16*)take((size_t)768 * 3072 * 2);
  bf16* xln  = (bf16*)take((size_t)2 * MP_ * 768 * 2);   // LN out, streams stacked
  char* R    = take((size_t)2 * MP_ * 3072 * 2);          // qkv / mlp-hidden union
  bf16* qkvb = (bf16*)R;                                  // [2MP][2304]
  bf16* hbuf = (bf16*)R;                                  // [2MP][3072]
  bf16* biasb = (bf16*)(R + (size_t)2 * MP_ * 2304 * 2);  // tail gap of R (8 MB < 14.5 MB free)
  bf16* Qcat = (bf16*)take((size_t)BH_ * NP_ * 128 * 2);
  bf16* Kcat = (bf16*)take((size_t)BH_ * NP_ * 128 * 2);
  bf16* Vt   = (bf16*)take((size_t)BH_ * 64 * NP_ * 2);
  bf16* CVt  = (bf16*)take((size_t)BH_ * 64 * NP_ * 2);
  float* rowt = (float*)take((size_t)BH_ * NP_ * 4);
  float* colt = (float*)take((size_t)BH_ * NP_ * 4);
  bf16* ctx  = (bf16*)take((size_t)2 * MP_ * 768 * 2);    // attn out, streams stacked

  float* outm = (float*)d_out;
  float* outc = outm + (size_t)M_ * D_;

  // weights + bias -> bf16
  cvt_kernel<<<(2304 * 768 + 255) / 256, 256, 0, stream>>>(qkvw, wq, 2304 * 768);
  cvt_kernel<<<(768 * 768 + 255) / 256, 256, 0, stream>>>(projw, wp, 768 * 768);
  cvt_kernel<<<(768 * 768 + 255) / 256, 256, 0, stream>>>(cprojw, wcp, 768 * 768);
  cvt_kernel<<<(3072 * 768 + 255) / 256, 256, 0, stream>>>(fc1w, wf1, 3072 * 768);
  cvt_kernel<<<(768 * 3072 + 255) / 256, 256, 0, stream>>>(fc2w, wf2, 768 * 3072);
  cvt_kernel<<<(H_ * N_ * N_ + 255) / 256, 256, 0, stream>>>(rpb, biasb, H_ * N_ * N_);
  // LN1 (streams stacked into xln)
  ln_kernel<<<M_, 256, 0, stream>>>(x_mean, n1w, n1b, xln);
  ln_kernel<<<M_, 256, 0, stream>>>(x_cov, n1w, n1b, xln + (size_t)MP_ * 768);
  // qkv GEMM (both streams, one dispatch)
  gemm_bt<EP_BF16><<<dim3(18, 74), 256, 0, stream>>>(xln, wq, wq, 2304, 768,
      nullptr, nullptr, nullptr, nullptr, nullptr, qkvb, nullptr, nullptr);
  // attention operand prep
  prep_kernel<<<dim3(10, 12, 8), 256, 0, stream>>>(
      qkvb, qkvb + (size_t)MP_ * 2304, Qcat, Kcat, Vt, CVt, rowt, colt);
  // fused attention (XCD-grouped 1-D grid)
  attn_kernel<<<960, 256, 0, stream>>>(Qcat, Kcat, Vt, CVt, rowt, colt, biasb,
                                       ctx, ctx + (size_t)MP_ * 768);
  // proj + residual (writes d_out), per-stream weights
  gemm_bt<EP_PROJ><<<dim3(6, 74), 256, 0, stream>>>(ctx, wp, wcp, 768, 768,
      projb, cprojb, g1, x_mean, x_cov, nullptr, outm, outc);
  // LN2 (reads d_out)
  ln_kernel<<<M_, 256, 0, stream>>>(outm, n2w, n2b, xln);
  ln_kernel<<<M_, 256, 0, stream>>>(outc, n2w, n2b, xln + (size_t)MP_ * 768);
  // fc1 + exact gelu (both streams)
  gemm_bt<EP_GELU><<<dim3(24, 74), 256, 0, stream>>>(xln, wf1, wf1, 3072, 768,
      fc1b, fc1b, nullptr, nullptr, nullptr, hbuf, nullptr, nullptr);
  // fc2, accumulate into d_out (both streams)
  gemm_bt<EP_FC2><<<dim3(6, 74), 256, 0, stream>>>(hbuf, wf2, wf2, 768, 3072,
      fc2b, fc2b, g2, nullptr, nullptr, nullptr, outm, outc);
}

// Round 3
// 400.981 us; speedup vs baseline: 1.7088x; 1.0918x over previous
//
#include <hip/hip_runtime.h>
#include <hip/hip_bf16.h>
#include <math.h>
#include <stdint.h>

typedef __bf16 bf16;
typedef __attribute__((ext_vector_type(8))) __bf16 bf16x8;
typedef __attribute__((ext_vector_type(4))) float f32x4;

typedef __attribute__((address_space(1))) void gas_void;
typedef __attribute__((address_space(3))) void las_void;

#define DEV __device__ __forceinline__

static constexpr int B_ = 8, N_ = 577, D_ = 768, H_ = 12;
static constexpr int M_ = B_ * N_;   // 4616 rows
static constexpr int MP_ = 4736;     // padded to 37*128 for GEMM tiles
static constexpr int NP_ = 640;      // padded N for attention tiles
static constexpr int BH_ = B_ * H_;  // 96
static constexpr float SCALE_ = 0.125f;  // 64^-0.5

DEV void async_cp16(const void* g, void* l) {
  __builtin_amdgcn_global_load_lds((gas_void*)g, (las_void*)l, 16, 0, 0);
}
DEV float fast_rcp(float x) { return __builtin_amdgcn_rcpf(x); }
DEV float elu1(float x) { return x > 0.0f ? x + 1.0f : __expf(x); }
// tanh-form GELU: x * sigmoid(1.5957691*x*(1 + 0.044715*x^2)); max dev ~1e-3
DEV float fast_gelu(float x) {
  const float x2 = x * x;
  const float z = x * fmaf(0.0713548826f, x2, 1.5957691216f);
  return x * fast_rcp(1.0f + __expf(-z));
}

// ---------------- f32 -> bf16 convert ----------------
__global__ __launch_bounds__(256) void cvt_kernel(const float* __restrict__ src,
                                                  bf16* __restrict__ dst, int n) {
  int i = blockIdx.x * 256 + threadIdx.x;
  if (i < n) dst[i] = (bf16)src[i];
}

// ---------------- LayerNorm (row of 768) -> bf16 ----------------
__global__ __launch_bounds__(256) void ln_kernel(const float* __restrict__ x,
                                                 const float* __restrict__ w,
                                                 const float* __restrict__ bp,
                                                 bf16* __restrict__ out) {
  const int row = blockIdx.x;
  const int t = threadIdx.x;
  const float* xr = x + (size_t)row * D_;
  float v0 = xr[t], v1 = xr[t + 256], v2 = xr[t + 512];
  float s = v0 + v1 + v2;
  float ss = v0 * v0 + v1 * v1 + v2 * v2;
#pragma unroll
  for (int m = 32; m >= 1; m >>= 1) {
    s += __shfl_down(s, m);
    ss += __shfl_down(ss, m);
  }
  __shared__ float red[8];
  if ((t & 63) == 0) { red[t >> 6] = s; red[4 + (t >> 6)] = ss; }
  __syncthreads();
  s = red[0] + red[1] + red[2] + red[3];
  ss = red[4] + red[5] + red[6] + red[7];
  const float mu = s * (1.0f / D_);
  float var = ss * (1.0f / D_) - mu * mu;
  var = fmaxf(var, 0.0f);
  const float rs = rsqrtf(var + 1e-5f);
  bf16* orow = out + (size_t)row * D_;
  orow[t]       = (bf16)((v0 - mu) * rs * w[t]       + bp[t]);
  orow[t + 256] = (bf16)((v1 - mu) * rs * w[t + 256] + bp[t + 256]);
  orow[t + 512] = (bf16)((v2 - mu) * rs * w[t + 512] + bp[t + 512]);
}

// ---------------- dual-stream GEMM: C[2MP,N] = A[2MP,K](bf16) * Ws[N,K]^T ----------------
// 2-phase double-buffered (stage t+1 before compute t; ONE barrier per k-step).
// 1-D grid + bijective XCD remap: consecutive blocks on an XCD share A-rows.
enum { EP_BF16 = 0, EP_PROJ = 1, EP_GELU = 2, EP_FC2 = 3 };

template <int EP>
__global__ __launch_bounds__(256) void gemm_bt(
    const bf16* __restrict__ A, const bf16* __restrict__ W0,
    const bf16* __restrict__ W1, int Nn, int K, int gx,
    const float* __restrict__ bias0, const float* __restrict__ bias1,
    const float* __restrict__ gamma,
    const float* __restrict__ resid0, const float* __restrict__ resid1,
    bf16* __restrict__ Cb, float* __restrict__ Cf0, float* __restrict__ Cf1) {
  __shared__ __align__(16) bf16 As[2][128 * 32];
  __shared__ __align__(16) bf16 Bs[2][128 * 32];
  // bijective XCD remap (m204): XCD k owns a contiguous range of tile ids
  const int nwg = gridDim.x;
  const int o = blockIdx.x;
  const int q = nwg >> 3, r = nwg & 7, xcd = o & 7;
  const int flat = (xcd < r ? xcd * (q + 1) : r * (q + 1) + (xcd - r) * q) + (o >> 3);
  const int bx = flat % gx, by = flat / gx;

  const int t = threadIdx.x;
  const int lane = t & 63, wv = t >> 6;
  const int ln = lane & 15, kg = lane >> 4;
  const int wr = wv >> 1, wc = wv & 1;
  const int s = (int)(by >= (MP_ / 128));
  const bf16* W = s ? W1 : W0;
  const size_t brow = (size_t)by * 128;
  const size_t bcol = (size_t)bx * 128;
  const int r0 = t >> 2, gsl = t & 3;
  const bf16* A0 = A + (brow + r0) * (size_t)K + gsl * 8;
  const bf16* A1 = A + (brow + r0 + 64) * (size_t)K + gsl * 8;
  const bf16* W0p = W + (bcol + r0) * (size_t)K + gsl * 8;
  const bf16* W1p = W + (bcol + r0 + 64) * (size_t)K + gsl * 8;

  auto stage = [&](int buf, int kk) {
    async_cp16(A0 + kk, &As[buf][(wv * 64) * 8]);
    async_cp16(A1 + kk, &As[buf][(256 + wv * 64) * 8]);
    async_cp16(W0p + kk, &Bs[buf][(wv * 64) * 8]);
    async_cp16(W1p + kk, &Bs[buf][(256 + wv * 64) * 8]);
  };

  f32x4 acc[4][4] = {};
  const int nt = K >> 5;
  stage(0, 0);
  __syncthreads();  // drain prologue stage
  int cur = 0;
  for (int tt = 0; tt < nt; ++tt) {
    if (tt + 1 < nt) stage(cur ^ 1, (tt + 1) * 32);
    bf16x8 af[4], bfr[4];
#pragma unroll
    for (int i = 0; i < 4; i++)
      af[i] = *(const bf16x8*)&As[cur][(wr * 64 + i * 16 + ln) * 32 + kg * 8];
#pragma unroll
    for (int j = 0; j < 4; j++)
      bfr[j] = *(const bf16x8*)&Bs[cur][(wc * 64 + j * 16 + ln) * 32 + kg * 8];
#pragma unroll
    for (int i = 0; i < 4; i++)
#pragma unroll
      for (int j = 0; j < 4; j++)
        acc[i][j] = __builtin_amdgcn_mfma_f32_16x16x32_bf16(af[i], bfr[j], acc[i][j], 0, 0, 0);
    __syncthreads();  // drains next-tile stage (compiler vmcnt(0)) + read fence
    cur ^= 1;
  }

  const float* biasS = s ? bias1 : bias0;
  const float* residS = s ? resid1 : resid0;
  float* CfS = s ? Cf1 : Cf0;
  // D layout: row = (lane>>4)*4 + r, col = lane&15
#pragma unroll
  for (int i = 0; i < 4; i++) {
    const int rb = (int)brow + wr * 64 + i * 16 + kg * 4;
#pragma unroll
    for (int j = 0; j < 4; j++) {
      const int col = (int)bcol + wc * 64 + j * 16 + ln;
#pragma unroll
      for (int rr = 0; rr < 4; rr++) {
        const int row = rb + rr;  // combined-row index
        float v = acc[i][j][rr];
        if (EP == EP_BF16) {
          Cb[(size_t)row * Nn + col] = (bf16)v;
        } else if (EP == EP_GELU) {
          v += biasS[col];
          Cb[(size_t)row * Nn + col] = (bf16)fast_gelu(v);
        } else {
          const int r2 = row - s * MP_;
          if (r2 < M_) {
            v += biasS[col];
            if (EP == EP_PROJ) {
              CfS[(size_t)r2 * Nn + col] = residS[(size_t)r2 * Nn + col] + gamma[col] * v;
            } else {  // EP_FC2
              CfS[(size_t)r2 * Nn + col] += gamma[col] * v;
            }
          }
        }
      }
    }
  }
}

// ---------------- prep: qkv (raw bf16) -> attention operands ----------------
__global__ __launch_bounds__(256) void prep_kernel(
    const bf16* __restrict__ qm, const bf16* __restrict__ qc,
    bf16* __restrict__ Qcat, bf16* __restrict__ Kcat,
    bf16* __restrict__ Vt, bf16* __restrict__ CVt,
    float* __restrict__ rowt, float* __restrict__ colt) {
  const int n0 = blockIdx.x * 64;
  const int h = blockIdx.y, b = blockIdx.z;
  const int bh = b * H_ + h;
  const int t = threadIdx.x;
  const int nl = t >> 2, c = t & 3;
  const int n = n0 + nl;
  const bool valid = n < N_;
  __shared__ bf16 vts[64][72], cvts[64][72];
  float q2 = 0.f, cqs = 0.f, k2 = 0.f, cks = 0.f;
  bf16 qo[16], sqo[16], ko[16], sko[16];
  if (valid) {
    const size_t ro = (size_t)(b * N_ + n) * 2304 + h * 64 + c * 16;
#pragma unroll
    for (int half = 0; half < 2; half++) {
      bf16x8 qv8 = *(const bf16x8*)(qm + ro + half * 8);
      bf16x8 kv8 = *(const bf16x8*)(qm + ro + 768 + half * 8);
      bf16x8 vv8 = *(const bf16x8*)(qm + ro + 1536 + half * 8);
      bf16x8 cq8 = *(const bf16x8*)(qc + ro + half * 8);
      bf16x8 ck8 = *(const bf16x8*)(qc + ro + 768 + half * 8);
      bf16x8 cv8 = *(const bf16x8*)(qc + ro + 1536 + half * 8);
#pragma unroll
      for (int i = 0; i < 8; i++) {
        const int d = half * 8 + i;
        float qv = (float)qv8[i] * SCALE_;
        float kv = (float)kv8[i];
        float cq1 = elu1((float)cq8[i]);
        float ck1 = elu1((float)ck8[i]);
        q2 += qv * qv; cqs += cq1; k2 += kv * kv; cks += ck1;
        qo[d] = (bf16)qv; sqo[d] = (bf16)sqrtf(fmaxf(cq1, 1e-24f));
        ko[d] = (bf16)kv; sko[d] = (bf16)sqrtf(fmaxf(ck1, 1e-24f));
        vts[nl][c * 16 + d] = vv8[i];
        cvts[nl][c * 16 + d] = (bf16)elu1((float)cv8[i]);
      }
    }
  } else {
#pragma unroll
    for (int d = 0; d < 16; d++) {
      qo[d] = (bf16)0.f; sqo[d] = (bf16)0.f; ko[d] = (bf16)0.f; sko[d] = (bf16)0.f;
      vts[nl][c * 16 + d] = (bf16)0.f; cvts[nl][c * 16 + d] = (bf16)0.f;
    }
  }
  {
    bf16* qrow = Qcat + ((size_t)bh * NP_ + n) * 128;
    bf16* krow = Kcat + ((size_t)bh * NP_ + n) * 128;
#pragma unroll
    for (int d = 0; d < 16; d++) {
      qrow[c * 16 + d] = qo[d];
      qrow[64 + c * 16 + d] = sqo[d];
      krow[c * 16 + d] = ko[d];
      krow[64 + c * 16 + d] = sko[d];
    }
  }
  float rt = q2 + cqs, ct = k2 + cks;
  rt += __shfl_xor(rt, 1); rt += __shfl_xor(rt, 2);
  ct += __shfl_xor(ct, 1); ct += __shfl_xor(ct, 2);
  if (c == 0) { rowt[(size_t)bh * NP_ + n] = rt; colt[(size_t)bh * NP_ + n] = ct; }
  __syncthreads();
  const int drow = t >> 2;
  const size_t vb = ((size_t)bh * 64 + drow) * NP_ + n0 + c * 16;
#pragma unroll
  for (int i = 0; i < 16; i++) {
    Vt[vb + i] = vts[c * 16 + i][drow];
    CVt[vb + i] = cvts[c * 16 + i][drow];
  }
}

// ---------------- fused attention ----------------
__global__ __launch_bounds__(256) void attn_kernel(
    const bf16* __restrict__ Qcat, const bf16* __restrict__ Kcat,
    const bf16* __restrict__ Vt, const bf16* __restrict__ CVt,
    const float* __restrict__ rowt, const float* __restrict__ colt,
    const bf16* __restrict__ bias,
    bf16* __restrict__ ctxm, bf16* __restrict__ ctxc) {
  const int id = blockIdx.x;            // 0..959
  const int xcd = id & 7, slot = id >> 3;
  const int g = xcd + 8 * (slot / 10);  // bh 0..95
  const int it = slot % 10;
  const int b = g / H_, h = g % H_;
  const int bh = g;
  const int i0 = it * 64;
  const int t = threadIdx.x;
  const int lane = t & 63, w = t >> 6;
  const int ln = lane & 15, kg = lane >> 4;
  __shared__ __align__(16) bf16 Ks[64 * 128];   // also used for Q staging
  __shared__ __align__(16) bf16 Vs[64 * 64];
  __shared__ __align__(16) bf16 CVs[64 * 64];
  __shared__ __align__(16) bf16 Ps[64 * 72];

  const bf16* Qg = Qcat + (size_t)bh * NP_ * 128;
  const bf16* Kg = Kcat + (size_t)bh * NP_ * 128;
  const bf16* Vg = Vt + (size_t)bh * 64 * NP_;
  const bf16* CVg = CVt + (size_t)bh * 64 * NP_;

#pragma unroll
  for (int qq = 0; qq < 4; qq++) {
    const int idx = qq * 256 + t;
    const int row = idx >> 4, sl = idx & 15;
    async_cp16(Qg + (size_t)(i0 + row) * 128 + ((sl ^ (row & 7)) * 8),
               &Ks[(qq * 256 + w * 64) * 8]);
  }
  __syncthreads();
  bf16x8 aq[4];
  {
    const int row = w * 16 + ln;
#pragma unroll
    for (int kc = 0; kc < 4; kc++) {
      const int slot2 = kc * 4 + kg;
      aq[kc] = *(const bf16x8*)&Ks[row * 128 + ((slot2 ^ (row & 7)) * 8)];
    }
  }
  float rt[4];
#pragma unroll
  for (int r = 0; r < 4; r++) rt[r] = rowt[(size_t)bh * NP_ + i0 + w * 16 + kg * 4 + r];

  f32x4 accm[4] = {}, accc[4] = {};
  float den[4] = {0.f, 0.f, 0.f, 0.f};
  const int igb = i0 + w * 16 + kg * 4;

  for (int jt = 0; jt < 10; jt++) {
    const int j0 = jt * 64;
    __syncthreads();
#pragma unroll
    for (int qq = 0; qq < 4; qq++) {
      const int idx = qq * 256 + t;
      const int row = idx >> 4, sl = idx & 15;
      async_cp16(Kg + (size_t)(j0 + row) * 128 + ((sl ^ (row & 7)) * 8),
                 &Ks[(qq * 256 + w * 64) * 8]);
    }
#pragma unroll
    for (int qq = 0; qq < 2; qq++) {
      const int idx = qq * 256 + t;
      const int row = idx >> 3, sl = idx & 7;
      async_cp16(Vg + (size_t)row * NP_ + j0 + ((sl ^ (row & 7)) * 8),
                 &Vs[(qq * 256 + w * 64) * 8]);
      async_cp16(CVg + (size_t)row * NP_ + j0 + ((sl ^ (row & 7)) * 8),
                 &CVs[(qq * 256 + w * 64) * 8]);
    }
    // prefetch bias + colt into regs (overlaps staging drain)
    float bb[4][4], ctb[4];
#pragma unroll
    for (int js = 0; js < 4; js++) {
      const int jg = j0 + js * 16 + ln;
      const int jc = jg < N_ ? jg : N_ - 1;
      ctb[js] = colt[(size_t)bh * NP_ + jg];
#pragma unroll
      for (int r = 0; r < 4; r++) {
        const int ic = (igb + r) < N_ ? (igb + r) : N_ - 1;
        bb[js][r] = (float)bias[((size_t)h * N_ + ic) * N_ + jc];
      }
    }
    __syncthreads();
#pragma unroll
    for (int js = 0; js < 4; js++) {
      f32x4 sv = {};
#pragma unroll
      for (int kc = 0; kc < 4; kc++) {
        const int row = js * 16 + ln;
        const int slot2 = kc * 4 + kg;
        bf16x8 bk = *(const bf16x8*)&Ks[row * 128 + ((slot2 ^ (row & 7)) * 8)];
        sv = __builtin_amdgcn_mfma_f32_16x16x32_bf16(aq[kc], bk, sv, 0, 0, 0);
      }
      const int jg = j0 + js * 16 + ln;
#pragma unroll
      for (int r = 0; r < 4; r++) {
        const float S = 2.0f * sv[r] - rt[r] - ctb[js];
        const float sig = fast_rcp(1.0f + __expf(-S));
        float e = __expf(sig + bb[js][r]);
        if (jg >= N_) e = 0.0f;
        const bf16 eb = (bf16)e;
        den[r] += (float)eb;
        Ps[(w * 16 + kg * 4 + r) * 72 + js * 16 + ln] = eb;
      }
    }
#pragma unroll
    for (int ks = 0; ks < 2; ks++) {
      const int prow = w * 16 + ln;
      bf16x8 pa = *(const bf16x8*)&Ps[prow * 72 + ks * 32 + kg * 8];
      bf16x8 p2a;
#pragma unroll
      for (int i = 0; i < 8; i++) {
        const float pf = (float)pa[i];
        p2a[i] = (bf16)(pf * pf);
      }
#pragma unroll
      for (int nt = 0; nt < 4; nt++) {
        const int vrow = nt * 16 + ln;
        const int slot2 = ks * 4 + kg;
        bf16x8 vb = *(const bf16x8*)&Vs[vrow * 64 + ((slot2 ^ (vrow & 7)) * 8)];
        bf16x8 cvb = *(const bf16x8*)&CVs[vrow * 64 + ((slot2 ^ (vrow & 7)) * 8)];
        accm[nt] = __builtin_amdgcn_mfma_f32_16x16x32_bf16(pa, vb, accm[nt], 0, 0, 0);
        accc[nt] = __builtin_amdgcn_mfma_f32_16x16x32_bf16(p2a, cvb, accc[nt], 0, 0, 0);
      }
    }
  }
#pragma unroll
  for (int r = 0; r < 4; r++) {
    float d = den[r];
    d += __shfl_xor(d, 1); d += __shfl_xor(d, 2);
    d += __shfl_xor(d, 4); d += __shfl_xor(d, 8);
    den[r] = d;
  }
#pragma unroll
  for (int r = 0; r < 4; r++) {
    const int ig = i0 + w * 16 + kg * 4 + r;
    if (ig < N_) {
      const float inv = fast_rcp(den[r]);
      const float inv2 = inv * inv;
      const size_t base = (size_t)(b * N_ + ig) * D_ + h * 64;
#pragma unroll
      for (int nt = 0; nt < 4; nt++) {
        ctxm[base + nt * 16 + ln] = (bf16)(accm[nt][r] * inv);
        ctxc[base + nt * 16 + ln] = (bf16)(accc[nt][r] * inv2);
      }
    }
  }
}

// ---------------- host launch ----------------
extern "C" void kernel_launch(void* const* d_in, const int* in_sizes, int n_in,
                              void* d_out, int out_size, void* d_ws, size_t ws_size,
                              hipStream_t stream) {
  const float* x_mean = (const float*)d_in[0];
  const float* x_cov  = (const float*)d_in[1];
  const float* rpb    = (const float*)d_in[2];
  const float* n1w    = (const float*)d_in[3];
  const float* n1b    = (const float*)d_in[4];
  const float* qkvw   = (const float*)d_in[5];
  const float* projw  = (const float*)d_in[6];
  const float* projb  = (const float*)d_in[7];
  const float* cprojw = (const float*)d_in[8];
  const float* cprojb = (const float*)d_in[9];
  const float* n2w    = (const float*)d_in[10];
  const float* n2b    = (const float*)d_in[11];
  const float* fc1w   = (const float*)d_in[12];
  const float* fc1b   = (const float*)d_in[13];
  const float* fc2w   = (const float*)d_in[14];
  const float* fc2b   = (const float*)d_in[15];
  const float* g1     = (const float*)d_in[16];
  const float* g2     = (const float*)d_in[17];
  (void)in_sizes; (void)n_in; (void)out_size; (void)ws_size;

  char* ws = (char*)d_ws;
  size_t off = 0;
  auto take = [&](size_t bytes) {
    char* p = ws + off;
    off += (bytes + 255) & ~(size_t)255;
    return p;
  };
  bf16* wq   = (bf16*)take((size_t)2304 * 768 * 2);
  bf16* wp   = (bf16*)take((size_t)768 * 768 * 2);
  bf16* wcp  = (bf16*)take((size_t)768 * 768 * 2);
  bf16* wf1  = (bf16*)take((size_t)3072 * 768 * 2);
  bf16* wf2  = (bf16*)take((size_t)768 * 3072 * 2);
  bf16* xln  = (bf16*)take((size_t)2 * MP_ * 768 * 2);   // LN out, streams stacked
  char* R    = take((size_t)2 * MP_ * 3072 * 2);          // qkv / mlp-hidden union
  bf16* qkvb = (bf16*)R;                                  // [2MP][2304]
  bf16* hbuf = (bf16*)R;                                  // [2MP][3072]
  bf16* biasb = (bf16*)(R + (size_t)2 * MP_ * 2304 * 2);  // tail gap of R
  bf16* Qcat = (bf16*)take((size_t)BH_ * NP_ * 128 * 2);
  bf16* Kcat = (bf16*)take((size_t)BH_ * NP_ * 128 * 2);
  bf16* Vt   = (bf16*)take((size_t)BH_ * 64 * NP_ * 2);
  bf16* CVt  = (bf16*)take((size_t)BH_ * 64 * NP_ * 2);
  float* rowt = (float*)take((size_t)BH_ * NP_ * 4);
  float* colt = (float*)take((size_t)BH_ * NP_ * 4);
  bf16* ctx  = (bf16*)take((size_t)2 * MP_ * 768 * 2);    // attn out, streams stacked

  float* outm = (float*)d_out;
  float* outc = outm + (size_t)M_ * D_;

  // weights + bias -> bf16
  cvt_kernel<<<(2304 * 768 + 255) / 256, 256, 0, stream>>>(qkvw, wq, 2304 * 768);
  cvt_kernel<<<(768 * 768 + 255) / 256, 256, 0, stream>>>(projw, wp, 768 * 768);
  cvt_kernel<<<(768 * 768 + 255) / 256, 256, 0, stream>>>(cprojw, wcp, 768 * 768);
  cvt_kernel<<<(3072 * 768 + 255) / 256, 256, 0, stream>>>(fc1w, wf1, 3072 * 768);
  cvt_kernel<<<(768 * 3072 + 255) / 256, 256, 0, stream>>>(fc2w, wf2, 768 * 3072);
  cvt_kernel<<<(H_ * N_ * N_ + 255) / 256, 256, 0, stream>>>(rpb, biasb, H_ * N_ * N_);
  // LN1 (streams stacked into xln)
  ln_kernel<<<M_, 256, 0, stream>>>(x_mean, n1w, n1b, xln);
  ln_kernel<<<M_, 256, 0, stream>>>(x_cov, n1w, n1b, xln + (size_t)MP_ * 768);
  // qkv GEMM (both streams, one dispatch)
  gemm_bt<EP_BF16><<<18 * 74, 256, 0, stream>>>(xln, wq, wq, 2304, 768, 18,
      nullptr, nullptr, nullptr, nullptr, nullptr, qkvb, nullptr, nullptr);
  // attention operand prep
  prep_kernel<<<dim3(10, 12, 8), 256, 0, stream>>>(
      qkvb, qkvb + (size_t)MP_ * 2304, Qcat, Kcat, Vt, CVt, rowt, colt);
  // fused attention (XCD-grouped 1-D grid)
  attn_kernel<<<960, 256, 0, stream>>>(Qcat, Kcat, Vt, CVt, rowt, colt, biasb,
                                       ctx, ctx + (size_t)MP_ * 768);
  // proj + residual (writes d_out), per-stream weights
  gemm_bt<EP_PROJ><<<6 * 74, 256, 0, stream>>>(ctx, wp, wcp, 768, 768, 6,
      projb, cprojb, g1, x_mean, x_cov, nullptr, outm, outc);
  // LN2 (reads d_out)
  ln_kernel<<<M_, 256, 0, stream>>>(outm, n2w, n2b, xln);
  ln_kernel<<<M_, 256, 0, stream>>>(outc, n2w, n2b, xln + (size_t)MP_ * 768);
  // fc1 + fast gelu (both streams)
  gemm_bt<EP_GELU><<<24 * 74, 256, 0, stream>>>(xln, wf1, wf1, 3072, 768, 24,
      fc1b, fc1b, nullptr, nullptr, nullptr, hbuf, nullptr, nullptr);
  // fc2, accumulate into d_out (both streams)
  gemm_bt<EP_FC2><<<6 * 74, 256, 0, stream>>>(hbuf, wf2, wf2, 768, 3072, 6,
      fc2b, fc2b, g2, nullptr, nullptr, nullptr, outm, outc);
}

// Round 4
// 385.721 us; speedup vs baseline: 1.7764x; 1.0396x over previous
//
#include <hip/hip_runtime.h>
#include <hip/hip_bf16.h>
#include <math.h>
#include <stdint.h>

typedef __bf16 bf16;
typedef __attribute__((ext_vector_type(8))) __bf16 bf16x8;
typedef __attribute__((ext_vector_type(4))) float f32x4;

typedef __attribute__((address_space(1))) void gas_void;
typedef __attribute__((address_space(3))) void las_void;

#define DEV __device__ __forceinline__

static constexpr int B_ = 8, N_ = 577, D_ = 768, H_ = 12;
static constexpr int M_ = B_ * N_;   // 4616 rows
static constexpr int MP_ = 4736;     // padded to 37*128 for GEMM tiles
static constexpr int NP_ = 640;      // padded N for attention tiles
static constexpr int BH_ = B_ * H_;  // 96
static constexpr float SCALE_ = 0.125f;  // 64^-0.5

DEV void async_cp16(const void* g, void* l) {
  __builtin_amdgcn_global_load_lds((gas_void*)g, (las_void*)l, 16, 0, 0);
}
DEV float fast_rcp(float x) { return __builtin_amdgcn_rcpf(x); }
DEV float elu1(float x) { return x > 0.0f ? x + 1.0f : __expf(x); }
// tanh-form GELU: x * sigmoid(1.5957691*x*(1 + 0.044715*x^2)); max dev ~1e-3
DEV float fast_gelu(float x) {
  const float x2 = x * x;
  const float z = x * fmaf(0.0713548826f, x2, 1.5957691216f);
  return x * fast_rcp(1.0f + __expf(-z));
}

// ---------------- f32 -> bf16 convert (vectorized) ----------------
__global__ __launch_bounds__(256) void cvt_kernel(const float* __restrict__ src,
                                                  bf16* __restrict__ dst, int n4) {
  const int i = blockIdx.x * 256 + threadIdx.x;
  if (i < n4) {
    const float4 v = ((const float4*)src)[i];
    bf16 o[4] = {(bf16)v.x, (bf16)v.y, (bf16)v.z, (bf16)v.w};
    *(uint64_t*)(dst + (size_t)i * 4) = *(const uint64_t*)o;
  }
}

// ---------------- LayerNorm (row of 768) -> bf16 ----------------
__global__ __launch_bounds__(256) void ln_kernel(const float* __restrict__ x,
                                                 const float* __restrict__ w,
                                                 const float* __restrict__ bp,
                                                 bf16* __restrict__ out) {
  const int row = blockIdx.x;
  const int t = threadIdx.x;
  const float* xr = x + (size_t)row * D_;
  float v0 = xr[t], v1 = xr[t + 256], v2 = xr[t + 512];
  float s = v0 + v1 + v2;
  float ss = v0 * v0 + v1 * v1 + v2 * v2;
#pragma unroll
  for (int m = 32; m >= 1; m >>= 1) {
    s += __shfl_down(s, m);
    ss += __shfl_down(ss, m);
  }
  __shared__ float red[8];
  if ((t & 63) == 0) { red[t >> 6] = s; red[4 + (t >> 6)] = ss; }
  __syncthreads();
  s = red[0] + red[1] + red[2] + red[3];
  ss = red[4] + red[5] + red[6] + red[7];
  const float mu = s * (1.0f / D_);
  float var = ss * (1.0f / D_) - mu * mu;
  var = fmaxf(var, 0.0f);
  const float rs = rsqrtf(var + 1e-5f);
  bf16* orow = out + (size_t)row * D_;
  orow[t]       = (bf16)((v0 - mu) * rs * w[t]       + bp[t]);
  orow[t + 256] = (bf16)((v1 - mu) * rs * w[t + 256] + bp[t + 256]);
  orow[t + 512] = (bf16)((v2 - mu) * rs * w[t + 512] + bp[t + 512]);
}

// ---------------- dual-stream GEMM: C[2MP,N] = A[2MP,K](bf16) * Ws[N,K]^T ----------------
// 3-buffer depth-2 pipeline: ONE raw s_barrier per k-step, counted
// s_waitcnt vmcnt(4) so the next tile's 4 loads stay in flight across the
// barrier (T4). Restage safety: buf written at iter t was last read at t-1,
// fenced by the barrier at top of iter t.
enum { EP_BF16 = 0, EP_PROJ = 1, EP_GELU = 2, EP_FC2 = 3 };

template <int EP, int K>
__global__ __launch_bounds__(256) void gemm_bt(
    const bf16* __restrict__ A, const bf16* __restrict__ W0,
    const bf16* __restrict__ W1, int Nn, int gx,
    const float* __restrict__ bias0, const float* __restrict__ bias1,
    const float* __restrict__ gamma,
    const float* __restrict__ resid0, const float* __restrict__ resid1,
    bf16* __restrict__ Cb, float* __restrict__ Cf0, float* __restrict__ Cf1) {
  __shared__ __align__(16) bf16 As[3][128 * 32];
  __shared__ __align__(16) bf16 Bs[3][128 * 32];
  // bijective XCD remap (m204): XCD k owns a contiguous range of tile ids
  const int nwg = gridDim.x;
  const int o = blockIdx.x;
  const int q = nwg >> 3, r = nwg & 7, xcd = o & 7;
  const int flat = (xcd < r ? xcd * (q + 1) : r * (q + 1) + (xcd - r) * q) + (o >> 3);
  const int bx = flat % gx, by = flat / gx;

  const int t = threadIdx.x;
  const int lane = t & 63, wv = t >> 6;
  const int ln = lane & 15, kg = lane >> 4;
  const int wr = wv >> 1, wc = wv & 1;
  const int s = (int)(by >= (MP_ / 128));
  const bf16* W = s ? W1 : W0;
  const size_t brow = (size_t)by * 128;
  const size_t bcol = (size_t)bx * 128;
  const int r0 = t >> 2, gsl = t & 3;
  const bf16* A0 = A + (brow + r0) * (size_t)K + gsl * 8;
  const bf16* A1 = A + (brow + r0 + 64) * (size_t)K + gsl * 8;
  const bf16* W0p = W + (bcol + r0) * (size_t)K + gsl * 8;
  const bf16* W1p = W + (bcol + r0 + 64) * (size_t)K + gsl * 8;

  auto stage = [&](int buf, int kk) {
    async_cp16(A0 + kk, &As[buf][(wv * 64) * 8]);
    async_cp16(A1 + kk, &As[buf][(256 + wv * 64) * 8]);
    async_cp16(W0p + kk, &Bs[buf][(wv * 64) * 8]);
    async_cp16(W1p + kk, &Bs[buf][(256 + wv * 64) * 8]);
  };

  f32x4 acc[4][4] = {};
  constexpr int nt = K >> 5;
  static_assert(nt % 3 == 0, "K/32 must be divisible by 3");
  stage(0, 0);
  stage(1, 32);
#pragma unroll 1
  for (int tb = 0; tb < nt; tb += 3) {
#pragma unroll
    for (int u = 0; u < 3; u++) {
      const int tt = tb + u;
      if (tt + 1 < nt) {
        asm volatile("s_waitcnt vmcnt(4)" ::: "memory");
      } else {
        asm volatile("s_waitcnt vmcnt(0)" ::: "memory");
      }
      __builtin_amdgcn_s_barrier();
      bf16x8 af[4], bfr[4];
#pragma unroll
      for (int i = 0; i < 4; i++)
        af[i] = *(const bf16x8*)&As[u][(wr * 64 + i * 16 + ln) * 32 + kg * 8];
#pragma unroll
      for (int j = 0; j < 4; j++)
        bfr[j] = *(const bf16x8*)&Bs[u][(wc * 64 + j * 16 + ln) * 32 + kg * 8];
#pragma unroll
      for (int i = 0; i < 4; i++)
#pragma unroll
        for (int j = 0; j < 4; j++)
          acc[i][j] = __builtin_amdgcn_mfma_f32_16x16x32_bf16(af[i], bfr[j], acc[i][j], 0, 0, 0);
      if (tt + 2 < nt) stage((u + 2) % 3, (tt + 2) * 32);
    }
  }

  const float* biasS = s ? bias1 : bias0;
  const float* residS = s ? resid1 : resid0;
  float* CfS = s ? Cf1 : Cf0;
  // D layout: row = (lane>>4)*4 + r, col = lane&15
#pragma unroll
  for (int i = 0; i < 4; i++) {
    const int rb = (int)brow + wr * 64 + i * 16 + kg * 4;
#pragma unroll
    for (int j = 0; j < 4; j++) {
      const int col = (int)bcol + wc * 64 + j * 16 + ln;
#pragma unroll
      for (int rr = 0; rr < 4; rr++) {
        const int row = rb + rr;  // combined-row index
        float v = acc[i][j][rr];
        if (EP == EP_BF16) {
          Cb[(size_t)row * Nn + col] = (bf16)v;
        } else if (EP == EP_GELU) {
          v += biasS[col];
          Cb[(size_t)row * Nn + col] = (bf16)fast_gelu(v);
        } else {
          const int r2 = row - s * MP_;
          if (r2 < M_) {
            v += biasS[col];
            if (EP == EP_PROJ) {
              CfS[(size_t)r2 * Nn + col] = residS[(size_t)r2 * Nn + col] + gamma[col] * v;
            } else {  // EP_FC2
              CfS[(size_t)r2 * Nn + col] += gamma[col] * v;
            }
          }
        }
      }
    }
  }
}

// ---------------- prep: qkv (raw bf16) -> attention operands ----------------
__global__ __launch_bounds__(256) void prep_kernel(
    const bf16* __restrict__ qm, const bf16* __restrict__ qc,
    bf16* __restrict__ Qcat, bf16* __restrict__ Kcat,
    bf16* __restrict__ Vt, bf16* __restrict__ CVt,
    float* __restrict__ rowt, float* __restrict__ colt) {
  const int n0 = blockIdx.x * 64;
  const int h = blockIdx.y, b = blockIdx.z;
  const int bh = b * H_ + h;
  const int t = threadIdx.x;
  const int nl = t >> 2, c = t & 3;
  const int n = n0 + nl;
  const bool valid = n < N_;
  __shared__ bf16 vts[64][72], cvts[64][72];
  float q2 = 0.f, cqs = 0.f, k2 = 0.f, cks = 0.f;
  bf16 qo[16], sqo[16], ko[16], sko[16];
  if (valid) {
    const size_t ro = (size_t)(b * N_ + n) * 2304 + h * 64 + c * 16;
#pragma unroll
    for (int half = 0; half < 2; half++) {
      bf16x8 qv8 = *(const bf16x8*)(qm + ro + half * 8);
      bf16x8 kv8 = *(const bf16x8*)(qm + ro + 768 + half * 8);
      bf16x8 vv8 = *(const bf16x8*)(qm + ro + 1536 + half * 8);
      bf16x8 cq8 = *(const bf16x8*)(qc + ro + half * 8);
      bf16x8 ck8 = *(const bf16x8*)(qc + ro + 768 + half * 8);
      bf16x8 cv8 = *(const bf16x8*)(qc + ro + 1536 + half * 8);
#pragma unroll
      for (int i = 0; i < 8; i++) {
        const int d = half * 8 + i;
        float qv = (float)qv8[i] * SCALE_;
        float kv = (float)kv8[i];
        float cq1 = elu1((float)cq8[i]);
        float ck1 = elu1((float)ck8[i]);
        q2 += qv * qv; cqs += cq1; k2 += kv * kv; cks += ck1;
        qo[d] = (bf16)qv; sqo[d] = (bf16)sqrtf(fmaxf(cq1, 1e-24f));
        ko[d] = (bf16)kv; sko[d] = (bf16)sqrtf(fmaxf(ck1, 1e-24f));
        vts[nl][c * 16 + d] = vv8[i];
        cvts[nl][c * 16 + d] = (bf16)elu1((float)cv8[i]);
      }
    }
  } else {
#pragma unroll
    for (int d = 0; d < 16; d++) {
      qo[d] = (bf16)0.f; sqo[d] = (bf16)0.f; ko[d] = (bf16)0.f; sko[d] = (bf16)0.f;
      vts[nl][c * 16 + d] = (bf16)0.f; cvts[nl][c * 16 + d] = (bf16)0.f;
    }
  }
  {
    bf16* qrow = Qcat + ((size_t)bh * NP_ + n) * 128;
    bf16* krow = Kcat + ((size_t)bh * NP_ + n) * 128;
#pragma unroll
    for (int d = 0; d < 16; d++) {
      qrow[c * 16 + d] = qo[d];
      qrow[64 + c * 16 + d] = sqo[d];
      krow[c * 16 + d] = ko[d];
      krow[64 + c * 16 + d] = sko[d];
    }
  }
  float rt = q2 + cqs, ct = k2 + cks;
  rt += __shfl_xor(rt, 1); rt += __shfl_xor(rt, 2);
  ct += __shfl_xor(ct, 1); ct += __shfl_xor(ct, 2);
  if (c == 0) { rowt[(size_t)bh * NP_ + n] = rt; colt[(size_t)bh * NP_ + n] = ct; }
  __syncthreads();
  const int drow = t >> 2;
  const size_t vb = ((size_t)bh * 64 + drow) * NP_ + n0 + c * 16;
#pragma unroll
  for (int i = 0; i < 16; i++) {
    Vt[vb + i] = vts[c * 16 + i][drow];
    CVt[vb + i] = cvts[c * 16 + i][drow];
  }
}

// ---------------- fused attention ----------------
__global__ __launch_bounds__(256) void attn_kernel(
    const bf16* __restrict__ Qcat, const bf16* __restrict__ Kcat,
    const bf16* __restrict__ Vt, const bf16* __restrict__ CVt,
    const float* __restrict__ rowt, const float* __restrict__ colt,
    const bf16* __restrict__ bias,
    bf16* __restrict__ ctxm, bf16* __restrict__ ctxc) {
  const int id = blockIdx.x;            // 0..959
  const int xcd = id & 7, slot = id >> 3;
  const int g = xcd + 8 * (slot / 10);  // bh 0..95
  const int it = slot % 10;
  const int b = g / H_, h = g % H_;
  const int bh = g;
  const int i0 = it * 64;
  const int t = threadIdx.x;
  const int lane = t & 63, w = t >> 6;
  const int ln = lane & 15, kg = lane >> 4;
  __shared__ __align__(16) bf16 Ks[64 * 128];   // also used for Q staging
  __shared__ __align__(16) bf16 Vs[64 * 64];
  __shared__ __align__(16) bf16 CVs[64 * 64];
  __shared__ __align__(16) bf16 Ps[64 * 72];

  const bf16* Qg = Qcat + (size_t)bh * NP_ * 128;
  const bf16* Kg = Kcat + (size_t)bh * NP_ * 128;
  const bf16* Vg = Vt + (size_t)bh * 64 * NP_;
  const bf16* CVg = CVt + (size_t)bh * 64 * NP_;

#pragma unroll
  for (int qq = 0; qq < 4; qq++) {
    const int idx = qq * 256 + t;
    const int row = idx >> 4, sl = idx & 15;
    async_cp16(Qg + (size_t)(i0 + row) * 128 + ((sl ^ (row & 7)) * 8),
               &Ks[(qq * 256 + w * 64) * 8]);
  }
  __syncthreads();
  bf16x8 aq[4];
  {
    const int row = w * 16 + ln;
#pragma unroll
    for (int kc = 0; kc < 4; kc++) {
      const int slot2 = kc * 4 + kg;
      aq[kc] = *(const bf16x8*)&Ks[row * 128 + ((slot2 ^ (row & 7)) * 8)];
    }
  }
  float rt[4];
#pragma unroll
  for (int r = 0; r < 4; r++) rt[r] = rowt[(size_t)bh * NP_ + i0 + w * 16 + kg * 4 + r];

  f32x4 accm[4] = {}, accc[4] = {};
  float den[4] = {0.f, 0.f, 0.f, 0.f};
  const int igb = i0 + w * 16 + kg * 4;

  for (int jt = 0; jt < 10; jt++) {
    const int j0 = jt * 64;
    __syncthreads();
#pragma unroll
    for (int qq = 0; qq < 4; qq++) {
      const int idx = qq * 256 + t;
      const int row = idx >> 4, sl = idx & 15;
      async_cp16(Kg + (size_t)(j0 + row) * 128 + ((sl ^ (row & 7)) * 8),
                 &Ks[(qq * 256 + w * 64) * 8]);
    }
#pragma unroll
    for (int qq = 0; qq < 2; qq++) {
      const int idx = qq * 256 + t;
      const int row = idx >> 3, sl = idx & 7;
      async_cp16(Vg + (size_t)row * NP_ + j0 + ((sl ^ (row & 7)) * 8),
                 &Vs[(qq * 256 + w * 64) * 8]);
      async_cp16(CVg + (size_t)row * NP_ + j0 + ((sl ^ (row & 7)) * 8),
                 &CVs[(qq * 256 + w * 64) * 8]);
    }
    // prefetch bias + colt into regs (overlaps staging drain)
    float bb[4][4], ctb[4];
#pragma unroll
    for (int js = 0; js < 4; js++) {
      const int jg = j0 + js * 16 + ln;
      const int jc = jg < N_ ? jg : N_ - 1;
      ctb[js] = colt[(size_t)bh * NP_ + jg];
#pragma unroll
      for (int r = 0; r < 4; r++) {
        const int ic = (igb + r) < N_ ? (igb + r) : N_ - 1;
        bb[js][r] = (float)bias[((size_t)h * N_ + ic) * N_ + jc];
      }
    }
    __syncthreads();
#pragma unroll
    for (int js = 0; js < 4; js++) {
      f32x4 sv = {};
#pragma unroll
      for (int kc = 0; kc < 4; kc++) {
        const int row = js * 16 + ln;
        const int slot2 = kc * 4 + kg;
        bf16x8 bk = *(const bf16x8*)&Ks[row * 128 + ((slot2 ^ (row & 7)) * 8)];
        sv = __builtin_amdgcn_mfma_f32_16x16x32_bf16(aq[kc], bk, sv, 0, 0, 0);
      }
      const int jg = j0 + js * 16 + ln;
#pragma unroll
      for (int r = 0; r < 4; r++) {
        const float S = 2.0f * sv[r] - rt[r] - ctb[js];
        const float sig = fast_rcp(1.0f + __expf(-S));
        float e = __expf(sig + bb[js][r]);
        if (jg >= N_) e = 0.0f;
        const bf16 eb = (bf16)e;
        den[r] += (float)eb;
        Ps[(w * 16 + kg * 4 + r) * 72 + js * 16 + ln] = eb;
      }
    }
#pragma unroll
    for (int ks = 0; ks < 2; ks++) {
      const int prow = w * 16 + ln;
      bf16x8 pa = *(const bf16x8*)&Ps[prow * 72 + ks * 32 + kg * 8];
      bf16x8 p2a;
#pragma unroll
      for (int i = 0; i < 8; i++) {
        const float pf = (float)pa[i];
        p2a[i] = (bf16)(pf * pf);
      }
#pragma unroll
      for (int nt = 0; nt < 4; nt++) {
        const int vrow = nt * 16 + ln;
        const int slot2 = ks * 4 + kg;
        bf16x8 vb = *(const bf16x8*)&Vs[vrow * 64 + ((slot2 ^ (vrow & 7)) * 8)];
        bf16x8 cvb = *(const bf16x8*)&CVs[vrow * 64 + ((slot2 ^ (vrow & 7)) * 8)];
        accm[nt] = __builtin_amdgcn_mfma_f32_16x16x32_bf16(pa, vb, accm[nt], 0, 0, 0);
        accc[nt] = __builtin_amdgcn_mfma_f32_16x16x32_bf16(p2a, cvb, accc[nt], 0, 0, 0);
      }
    }
  }
#pragma unroll
  for (int r = 0; r < 4; r++) {
    float d = den[r];
    d += __shfl_xor(d, 1); d += __shfl_xor(d, 2);
    d += __shfl_xor(d, 4); d += __shfl_xor(d, 8);
    den[r] = d;
  }
#pragma unroll
  for (int r = 0; r < 4; r++) {
    const int ig = i0 + w * 16 + kg * 4 + r;
    if (ig < N_) {
      const float inv = fast_rcp(den[r]);
      const float inv2 = inv * inv;
      const size_t base = (size_t)(b * N_ + ig) * D_ + h * 64;
#pragma unroll
      for (int nt = 0; nt < 4; nt++) {
        ctxm[base + nt * 16 + ln] = (bf16)(accm[nt][r] * inv);
        ctxc[base + nt * 16 + ln] = (bf16)(accc[nt][r] * inv2);
      }
    }
  }
}

// ---------------- host launch ----------------
extern "C" void kernel_launch(void* const* d_in, const int* in_sizes, int n_in,
                              void* d_out, int out_size, void* d_ws, size_t ws_size,
                              hipStream_t stream) {
  const float* x_mean = (const float*)d_in[0];
  const float* x_cov  = (const float*)d_in[1];
  const float* rpb    = (const float*)d_in[2];
  const float* n1w    = (const float*)d_in[3];
  const float* n1b    = (const float*)d_in[4];
  const float* qkvw   = (const float*)d_in[5];
  const float* projw  = (const float*)d_in[6];
  const float* projb  = (const float*)d_in[7];
  const float* cprojw = (const float*)d_in[8];
  const float* cprojb = (const float*)d_in[9];
  const float* n2w    = (const float*)d_in[10];
  const float* n2b    = (const float*)d_in[11];
  const float* fc1w   = (const float*)d_in[12];
  const float* fc1b   = (const float*)d_in[13];
  const float* fc2w   = (const float*)d_in[14];
  const float* fc2b   = (const float*)d_in[15];
  const float* g1     = (const float*)d_in[16];
  const float* g2     = (const float*)d_in[17];
  (void)in_sizes; (void)n_in; (void)out_size; (void)ws_size;

  char* ws = (char*)d_ws;
  size_t off = 0;
  auto take = [&](size_t bytes) {
    char* p = ws + off;
    off += (bytes + 255) & ~(size_t)255;
    return p;
  };
  bf16* wq   = (bf16*)take((size_t)2304 * 768 * 2);
  bf16* wp   = (bf16*)take((size_t)768 * 768 * 2);
  bf16* wcp  = (bf16*)take((size_t)768 * 768 * 2);
  bf16* wf1  = (bf16*)take((size_t)3072 * 768 * 2);
  bf16* wf2  = (bf16*)take((size_t)768 * 3072 * 2);
  bf16* xln  = (bf16*)take((size_t)2 * MP_ * 768 * 2);   // LN out, streams stacked
  char* R    = take((size_t)2 * MP_ * 3072 * 2);          // qkv / mlp-hidden union
  bf16* qkvb = (bf16*)R;                                  // [2MP][2304]
  bf16* hbuf = (bf16*)R;                                  // [2MP][3072]
  bf16* biasb = (bf16*)(R + (size_t)2 * MP_ * 2304 * 2);  // tail gap of R
  bf16* Qcat = (bf16*)take((size_t)BH_ * NP_ * 128 * 2);
  bf16* Kcat = (bf16*)take((size_t)BH_ * NP_ * 128 * 2);
  bf16* Vt   = (bf16*)take((size_t)BH_ * 64 * NP_ * 2);
  bf16* CVt  = (bf16*)take((size_t)BH_ * 64 * NP_ * 2);
  float* rowt = (float*)take((size_t)BH_ * NP_ * 4);
  float* colt = (float*)take((size_t)BH_ * NP_ * 4);
  bf16* ctx  = (bf16*)take((size_t)2 * MP_ * 768 * 2);    // attn out, streams stacked

  float* outm = (float*)d_out;
  float* outc = outm + (size_t)M_ * D_;

  // weights + bias -> bf16 (vectorized, n divisible by 4 for all)
  cvt_kernel<<<(2304 * 768 / 4 + 255) / 256, 256, 0, stream>>>(qkvw, wq, 2304 * 768 / 4);
  cvt_kernel<<<(768 * 768 / 4 + 255) / 256, 256, 0, stream>>>(projw, wp, 768 * 768 / 4);
  cvt_kernel<<<(768 * 768 / 4 + 255) / 256, 256, 0, stream>>>(cprojw, wcp, 768 * 768 / 4);
  cvt_kernel<<<(3072 * 768 / 4 + 255) / 256, 256, 0, stream>>>(fc1w, wf1, 3072 * 768 / 4);
  cvt_kernel<<<(768 * 3072 / 4 + 255) / 256, 256, 0, stream>>>(fc2w, wf2, 768 * 3072 / 4);
  cvt_kernel<<<(H_ * N_ * N_ / 4 + 255) / 256, 256, 0, stream>>>(rpb, biasb, H_ * N_ * N_ / 4);
  // LN1 (streams stacked into xln)
  ln_kernel<<<M_, 256, 0, stream>>>(x_mean, n1w, n1b, xln);
  ln_kernel<<<M_, 256, 0, stream>>>(x_cov, n1w, n1b, xln + (size_t)MP_ * 768);
  // qkv GEMM (both streams, one dispatch)
  gemm_bt<EP_BF16, 768><<<18 * 74, 256, 0, stream>>>(xln, wq, wq, 2304, 18,
      nullptr, nullptr, nullptr, nullptr, nullptr, qkvb, nullptr, nullptr);
  // attention operand prep
  prep_kernel<<<dim3(10, 12, 8), 256, 0, stream>>>(
      qkvb, qkvb + (size_t)MP_ * 2304, Qcat, Kcat, Vt, CVt, rowt, colt);
  // fused attention (XCD-grouped 1-D grid)
  attn_kernel<<<960, 256, 0, stream>>>(Qcat, Kcat, Vt, CVt, rowt, colt, biasb,
                                       ctx, ctx + (size_t)MP_ * 768);
  // proj + residual (writes d_out), per-stream weights
  gemm_bt<EP_PROJ, 768><<<6 * 74, 256, 0, stream>>>(ctx, wp, wcp, 768, 6,
      projb, cprojb, g1, x_mean, x_cov, nullptr, outm, outc);
  // LN2 (reads d_out)
  ln_kernel<<<M_, 256, 0, stream>>>(outm, n2w, n2b, xln);
  ln_kernel<<<M_, 256, 0, stream>>>(outc, n2w, n2b, xln + (size_t)MP_ * 768);
  // fc1 + fast gelu (both streams)
  gemm_bt<EP_GELU, 768><<<24 * 74, 256, 0, stream>>>(xln, wf1, wf1, 3072, 24,
      fc1b, fc1b, nullptr, nullptr, nullptr, hbuf, nullptr, nullptr);
  // fc2, accumulate into d_out (both streams)
  gemm_bt<EP_FC2, 3072><<<6 * 74, 256, 0, stream>>>(hbuf, wf2, wf2, 768, 6,
      fc2b, fc2b, g2, nullptr, nullptr, nullptr, outm, outc);
}